// Round 9
// baseline (192.385 us; speedup 1.0000x reference)
//
#include <hip/hip_runtime.h>
#include <cstdint>

#define NEG (-1e12f)
constexpr int Bn = 32, Ln = 256, Tn = 2048;
constexpr int TB = Tn / 64;                 // 32 uint64 words of t-bits per text row

// d_ws layout (bytes):
//   bits    @ 0       : 32*256*32*8 = 2,097,152
//   partial @ 2097152 : 1024 floats (4 KB)
//   ext     @ 2101248 : 8192 int2  (64 KB)

// lane i <- lane (i-1)&63  (wave_ror:1) : torch-wrap neighbor for the bit compare
__device__ inline float dpp_ror1(float x) {
    int xi = __float_as_int(x);
    return __int_as_float(__builtin_amdgcn_update_dpp(xi, xi, 0x13C, 0xF, 0xF, false));
}
// lane i <- lane i-1, lane 0 <- old  (wave_shr:1) : DP 'left' input directly
__device__ inline float dpp_shr1(float x, float old) {
    return __int_as_float(__builtin_amdgcn_update_dpp(
        __float_as_int(old), __float_as_int(x), 0x138, 0xF, 0xF, false));
}

__device__ inline uint32_t lds_off(const void* p) {
    return (uint32_t)(uintptr_t)(__attribute__((address_space(3))) const void*)p;
}

// raw barrier: NO implicit counter drain (producers' global loads stay in flight)
#define BARRIER() { asm volatile("" ::: "memory"); \
                    __builtin_amdgcn_s_barrier(); \
                    asm volatile("" ::: "memory"); }

// swizzled ds_read_b128: ROW = row within buffer (0..15), BUF = ring buffer (0..3).
// Element (t,l) lives at col l ^ (16*bit2(t)); block byte = (16*lane) ^ (64*bit2(row)).
#define DSRX(DST, ROW, BUF) \
    asm volatile("ds_read_b128 %0, %1 offset:%c2" \
        : "=&v"(DST) \
        : "v"((((ROW) >> 2) & 1) ? vxb : vxa), \
          "i"((BUF) * 16384 + ((ROW) & 15) * 1024));

// consume gate: 16 slots outstanding -> oldest landed; fence non-asm hoisting (rule #18)
#define W15 { asm volatile("s_waitcnt lgkmcnt(15)"); __builtin_amdgcn_sched_barrier(0); }

// S = t - 64m (1..64) compile-time; Q = slot float4 for this step
#define STEPS(S, Q) { \
    float c3 = fmaxf(pv3, pv2) + (Q).w; \
    float c2 = fmaxf(pv2, pv1) + (Q).z; \
    float c1 = fmaxf(pv1, pv0) + (Q).y; \
    float c0 = fmaxf(pv0, left) + (Q).x; \
    float sv = dpp_ror1(c3); \
    left = dpp_shr1(c3, negc); \
    uint32_t e0 = __float_as_uint(c0 - sv) >> 31; \
    uint32_t e1 = __float_as_uint(c1 - c0) >> 31; \
    uint32_t e2 = __float_as_uint(c2 - c1) >> 31; \
    uint32_t e3 = __float_as_uint(c3 - c2) >> 31; \
    if (((S) & 32) == 0) { \
        a0lo |= e0 << ((S) & 31); a1lo |= e1 << ((S) & 31); \
        a2lo |= e2 << ((S) & 31); a3lo |= e3 << ((S) & 31); \
    } else { \
        a0hi |= e0 << ((S) & 31); a1hi |= e1 << ((S) & 31); \
        a2hi |= e2 << ((S) & 31); a3hi |= e3 << ((S) & 31); \
    } \
    if ((S) == 63) { \
        bb[(size_t)(4 * lane + 0) * TB + m] = ((uint64_t)a0hi << 32) | a0lo; \
        bb[(size_t)(4 * lane + 1) * TB + m] = ((uint64_t)a1hi << 32) | a1lo; \
        bb[(size_t)(4 * lane + 2) * TB + m] = ((uint64_t)a2hi << 32) | a2lo; \
        bb[(size_t)(4 * lane + 3) * TB + m] = ((uint64_t)a3hi << 32) | a3lo; \
        a0lo = a0hi = a1lo = a1hi = a2lo = a2hi = a3lo = a3hi = 0; \
    } \
    pv0 = c0; pv1 = c1; pv2 = c2; pv3 = c3; }

// 16 DP steps of chunk c = 4m+I (buffer I). 16-slot pipeline: step k consumes slot
// k-1 (pre-issued 16 steps ago) and reissues it for row k of chunk c+1 (k<=15).
// Chunk c+2 row 0 is issued AFTER the barrier (producers just finished writing it).
#define COMP16X(I) { \
    W15 STEPS(16*(I)+ 1, qq0)  DSRX(qq0,  1, ((I)+1)&3) \
    W15 STEPS(16*(I)+ 2, qq1)  DSRX(qq1,  2, ((I)+1)&3) \
    W15 STEPS(16*(I)+ 3, qq2)  DSRX(qq2,  3, ((I)+1)&3) \
    W15 STEPS(16*(I)+ 4, qq3)  DSRX(qq3,  4, ((I)+1)&3) \
    W15 STEPS(16*(I)+ 5, qq4)  DSRX(qq4,  5, ((I)+1)&3) \
    W15 STEPS(16*(I)+ 6, qq5)  DSRX(qq5,  6, ((I)+1)&3) \
    W15 STEPS(16*(I)+ 7, qq6)  DSRX(qq6,  7, ((I)+1)&3) \
    W15 STEPS(16*(I)+ 8, qq7)  DSRX(qq7,  8, ((I)+1)&3) \
    W15 STEPS(16*(I)+ 9, qq8)  DSRX(qq8,  9, ((I)+1)&3) \
    W15 STEPS(16*(I)+10, qq9)  DSRX(qq9, 10, ((I)+1)&3) \
    W15 STEPS(16*(I)+11, qq10) DSRX(qq10,11, ((I)+1)&3) \
    W15 STEPS(16*(I)+12, qq11) DSRX(qq11,12, ((I)+1)&3) \
    W15 STEPS(16*(I)+13, qq12) DSRX(qq12,13, ((I)+1)&3) \
    W15 STEPS(16*(I)+14, qq13) DSRX(qq13,14, ((I)+1)&3) \
    W15 STEPS(16*(I)+15, qq14) DSRX(qq14,15, ((I)+1)&3) \
    W15 STEPS(16*(I)+16, qq15) \
    BARRIER() \
    DSRX(qq15, 0, ((I)+2)&3) \
}

// producer reg-staged load of chunk P (t = 16P..16P+15), 6 float4 per thread
#define PLOAD(P) { \
    xh0 = *(const float4*)(pr0 + 16 * (P)); \
    xh1 = *(const float4*)(pr1 + 16 * (P)); \
    xh2 = *(const float4*)(pr2 + 16 * (P)); \
    xh3 = *(const float4*)(pr3 + 16 * (P)); \
    xh4 = *(const float4*)(pr4 + 16 * (P)); \
    if (six) xh5 = *(const float4*)(pr5 + 16 * (P)); }

#define PW1(XH, CC) { float* rq = rr + (CC); \
    rq[0] = (XH).x; rq[256] = (XH).y; rq[512] = (XH).z; rq[768] = (XH).w; }

#define PWRITE(P) { \
    float* rr = smem + ((P) & 3) * 4096; \
    PW1(xh0, c0) PW1(xh1, c1) PW1(xh2, c2) PW1(xh3, c3) PW1(xh4, c4) \
    if (six) PW1(xh5, c5) }

// ===== mega kernel: blocks 0..31 forward+staging+backtrack | 32..1055 loss =====
__global__ void __launch_bounds__(256, 1) k_mega(
        const float* __restrict__ logp, const float* __restrict__ att,
        const int* __restrict__ ilen, const int* __restrict__ olen,
        uint64_t* __restrict__ bits, float* __restrict__ partial,
        int2* __restrict__ ext) {
    __shared__ __align__(16) float smem[16384];   // 64 KB: 4 ring buffers x 16 t x 256 l
    int bid = blockIdx.x, tid = threadIdx.x;

    if (bid < 32) {
        int b = bid;
        if (tid < 64) {
            // ---------------- DP consumer wave ----------------
            __builtin_amdgcn_s_setprio(1);
            int lane = tid;
            uint64_t* bb = bits + (size_t)b * (Ln * TB);
            const float negc = NEG;
            uint32_t lb = lds_off(smem) + (uint32_t)(lane * 16);
            uint32_t vxa = lb, vxb = lb ^ 64;     // swizzle base pair

            float pv0, pv1, pv2, pv3, left;
            uint32_t a0lo = 0, a0hi = 0, a1lo = 0, a1hi = 0;
            uint32_t a2lo = 0, a2hi = 0, a3lo = 0, a3hi = 0;

            // peeled t = 0: row0 = logp[b,0,0], others NEG; seed bit 0 of word 0
            {
                float lp00 = logp[(size_t)b * (Ln * Tn)];
                float n0 = (lane == 0) ? lp00 : NEG;
                float n1 = NEG, n2 = NEG, n3 = NEG;
                float sv = dpp_ror1(n3);
                a0lo |= __float_as_uint(n0 - sv) >> 31;
                a1lo |= __float_as_uint(n1 - n0) >> 31;
                a2lo |= __float_as_uint(n2 - n1) >> 31;
                a3lo |= __float_as_uint(n3 - n2) >> 31;
                left = NEG;
                pv0 = n0; pv1 = n1; pv2 = n2; pv3 = n3;
            }

            BARRIER();                         // chunks 0,1 in LDS; chunk 2 staged in regs
            float4 qq0, qq1, qq2, qq3, qq4, qq5, qq6, qq7;
            float4 qq8, qq9, qq10, qq11, qq12, qq13, qq14, qq15;
            DSRX(qq0,  1, 0) DSRX(qq1,  2, 0) DSRX(qq2,  3, 0) DSRX(qq3,  4, 0)
            DSRX(qq4,  5, 0) DSRX(qq5,  6, 0) DSRX(qq6,  7, 0) DSRX(qq7,  8, 0)
            DSRX(qq8,  9, 0) DSRX(qq9, 10, 0) DSRX(qq10,11, 0) DSRX(qq11,12, 0)
            DSRX(qq12,13, 0) DSRX(qq13,14, 0) DSRX(qq14,15, 0) DSRX(qq15, 0, 1)

            #pragma unroll 1
            for (int m = 0; m < 32; ++m) {
                COMP16X(0) COMP16X(1) COMP16X(2) COMP16X(3)
            }
            asm volatile("s_waitcnt vmcnt(0)" ::: "memory");  // bit flushes visible
        } else {
            // -------- producer waves: stage logp -> LDS ring, transposed + swizzled --------
            int tid2 = tid - 64;                         // 0..191
            bool six = (tid2 < 64);                      // wave-uniform extra element
            const float* lpb = logp + (size_t)b * (Ln * Tn);
            int v0 = tid2, v1 = tid2 + 192, v2 = tid2 + 384,
                v3 = tid2 + 576, v4 = tid2 + 768, v5 = tid2 + 960;
            const float* pr0 = lpb + (size_t)(v0 >> 2) * Tn + 4 * (v0 & 3);
            const float* pr1 = lpb + (size_t)(v1 >> 2) * Tn + 4 * (v1 & 3);
            const float* pr2 = lpb + (size_t)(v2 >> 2) * Tn + 4 * (v2 & 3);
            const float* pr3 = lpb + (size_t)(v3 >> 2) * Tn + 4 * (v3 & 3);
            const float* pr4 = lpb + (size_t)(v4 >> 2) * Tn + 4 * (v4 & 3);
            const float* pr5 = lpb + (size_t)(v5 >> 2) * Tn + 4 * (v5 & 3);
            // col = l ^ (16*bit2(t)); bit2(t) = v&1 for this mapping -> per-slot constant
            int c0 = (4 * (v0 & 3)) * 256 + ((v0 >> 2) ^ ((v0 & 1) << 4));
            int c1 = (4 * (v1 & 3)) * 256 + ((v1 >> 2) ^ ((v1 & 1) << 4));
            int c2 = (4 * (v2 & 3)) * 256 + ((v2 >> 2) ^ ((v2 & 1) << 4));
            int c3 = (4 * (v3 & 3)) * 256 + ((v3 >> 2) ^ ((v3 & 1) << 4));
            int c4 = (4 * (v4 & 3)) * 256 + ((v4 >> 2) ^ ((v4 & 1) << 4));
            int c5 = (4 * (v5 & 3)) * 256 + ((v5 >> 2) ^ ((v5 & 1) << 4));
            float4 xh0, xh1, xh2, xh3, xh4, xh5;

            PLOAD(0) PWRITE(0)                 // prologue: chunks 0,1 in LDS; chunk 2 in regs
            PLOAD(1) PWRITE(1)
            PLOAD(2)
            asm volatile("s_waitcnt lgkmcnt(0)" ::: "memory");
            BARRIER();

            #pragma unroll 1
            for (int k = 0; k < 128; ++k) {
                if (k <= 125) PWRITE(k + 2)    // write chunk staged last iteration
                if (k <= 124) PLOAD(k + 3)     // loads span the barrier (raw s_barrier)
                asm volatile("s_waitcnt lgkmcnt(0)" ::: "memory");
                BARRIER();
            }
        }

        // ---------------- fused backtrack (all 256 threads converge) ----------------
        BARRIER();                              // consumer's flush stores drained above
        int2* eb = ext + b * Ln;
        eb[tid] = make_int2(1, 0);              // init extents to empty
        const ulonglong2* g2 = (const ulonglong2*)(bits + (size_t)b * (Ln * TB));
        ulonglong2* s2 = (ulonglong2*)smem;     // ring buffers dead; reuse as bit store
        #pragma unroll
        for (int i = 0; i < 16; ++i) s2[i * 256 + tid] = g2[i * 256 + tid];
        __syncthreads();
        if (tid == 0) {
            const uint64_t* sb = (const uint64_t*)smem;
            int tl = ilen[b], ml = olen[b];
            int r = tl - 1, hi = ml - 1, p = ml - 2;
            if (p < 0) { eb[r] = make_int2(0, hi); return; }
            int c = p >> 6;
            uint64_t w0 = sb[r * TB + c];
            uint64_t w1 = sb[(r > 0 ? r - 1 : 0) * TB + c];
            uint64_t w2 = sb[(r > 1 ? r - 2 : 0) * TB + c];
            uint64_t w3 = sb[(r > 2 ? r - 3 : 0) * TB + c];
            int vd = 3;
            while (true) {
                int pb = p & 63;
                uint64_t mask = (pb == 63) ? ~0ull : ((1ull << (pb + 1)) - 1ull);
                uint64_t mm = w0 & mask;
                if (mm == 0) {
                    p = (p & ~63) - 1;
                    if (p < 0) { eb[r] = make_int2(0, hi); break; }
                    c = p >> 6;
                    w0 = sb[r * TB + c];
                    w1 = sb[(r > 0 ? r - 1 : 0) * TB + c];
                    w2 = sb[(r > 1 ? r - 2 : 0) * TB + c];
                    w3 = sb[(r > 2 ? r - 3 : 0) * TB + c];
                    vd = 3;
                } else {
                    int q = 63 - __builtin_clzll(mm);
                    int tq = (p & ~63) + q;
                    eb[r] = make_int2(tq + 1, hi);
                    r -= 1;
                    if (r < 0) break;           // saturation: remaining columns zero
                    hi = tq;
                    p = tq - 1;
                    if (p < 0) { eb[r] = make_int2(0, hi); break; }
                    w0 = w1; w1 = w2; w2 = w3; vd -= 1;
                    int nc = p >> 6;
                    if (nc != c || vd == 0) {
                        c = nc;
                        w0 = sb[r * TB + c];
                        w1 = sb[(r > 0 ? r - 1 : 0) * TB + c];
                        w2 = sb[(r > 1 ? r - 2 : 0) * TB + c];
                        w3 = sb[(r > 2 ? r - 3 : 0) * TB + c];
                        vd = 3;
                    }
                }
            }
        }
    } else {
        // ---------------- guided-attention loss partials (independent blocks) ----------------
        const int N4 = Bn * Tn * Ln / 4;
        int j = bid - 32;
        int idx = j * 256 + tid;
        int stride = 1024 * 256;
        float acc = 0.f;
        for (int v = idx; v < N4; v += stride) {
            int flat = v << 2;                   // att is (B, T, L)
            int b  = flat >> 19;
            int t  = (flat >> 8) & (Tn - 1);
            int l0 = flat & (Ln - 1);
            int ili = ilen[b];
            int oli = olen[b];
            if (t >= oli) continue;
            float il = (float)ili, ol = (float)oli;
            float tf = (float)t / ol;
            float4 a = reinterpret_cast<const float4*>(att)[v];
            #pragma unroll
            for (int c = 0; c < 4; ++c) {
                int l = l0 + c;
                float av = (c == 0) ? a.x : (c == 1) ? a.y : (c == 2) ? a.z : a.w;
                if (l < ili) {
                    float d = (float)l / il - tf;
                    acc += (1.f - __expf(-d * d * 3.125f)) * av;
                }
            }
        }
        for (int off = 32; off > 0; off >>= 1) acc += __shfl_down(acc, off, 64);
        float* sw = smem;
        if ((tid & 63) == 0) sw[tid >> 6] = acc;
        __syncthreads();
        if (tid == 0) partial[j] = (sw[0] + sw[1]) + (sw[2] + sw[3]);
    }
}

// ---------------- aligned-float4 fill from extents + fused final loss reduce ----------------
__global__ void k_fill(const int2* __restrict__ ext, const float* __restrict__ partial,
                       const int* __restrict__ olen, float* __restrict__ out) {
    const int NG = (Bn * Ln * Tn) / 4;          // 4,194,304 aligned float4 groups
    int idx = blockIdx.x * blockDim.x + threadIdx.x;
    int stride = gridDim.x * blockDim.x;
    for (int i = idx; i < NG; i += stride) {
        if (i == 0) {
            int2 e = ext[0];                     // out[1..3] = align f=0..2 (row 0)
            out[1] = (0 >= e.x && 0 <= e.y) ? 1.f : 0.f;
            out[2] = (1 >= e.x && 1 <= e.y) ? 1.f : 0.f;
            out[3] = (2 >= e.x && 2 <= e.y) ? 1.f : 0.f;
            int2 el = ext[Bn * Ln - 1];          // last element: row 8191, t=2047
            out[(size_t)Bn * Ln * Tn] = (2047 >= el.x && 2047 <= el.y) ? 1.f : 0.f;
            continue;
        }
        int f0 = 4 * i - 1;                      // align flat index of out[4i]
        int r0 = f0 >> 11;
        int t0 = f0 & 2047;
        int2 e0 = ext[r0];
        float4 v;
        if (t0 != 2047) {                        // all 4 in row r0
            v.x = (t0     >= e0.x && t0     <= e0.y) ? 1.f : 0.f;
            v.y = (t0 + 1 >= e0.x && t0 + 1 <= e0.y) ? 1.f : 0.f;
            v.z = (t0 + 2 >= e0.x && t0 + 2 <= e0.y) ? 1.f : 0.f;
            v.w = (t0 + 3 >= e0.x && t0 + 3 <= e0.y) ? 1.f : 0.f;
        } else {                                 // crosses into row r0+1 (t=0,1,2)
            int2 e1 = ext[r0 + 1];
            v.x = (2047 >= e0.x && 2047 <= e0.y) ? 1.f : 0.f;
            v.y = (0 >= e1.x && 0 <= e1.y) ? 1.f : 0.f;
            v.z = (1 >= e1.x && 1 <= e1.y) ? 1.f : 0.f;
            v.w = (2 >= e1.x && 2 <= e1.y) ? 1.f : 0.f;
        }
        *reinterpret_cast<float4*>(out + (size_t)4 * i) = v;
    }
    if (blockIdx.x == 0) {                       // fused deterministic loss reduce
        int tid = threadIdx.x;
        float acc = 0.f;
        for (int i = tid; i < 1024; i += 256) acc += partial[i];
        for (int off = 32; off > 0; off >>= 1) acc += __shfl_down(acc, off, 64);
        __shared__ float sw[4];
        if ((tid & 63) == 0) sw[tid >> 6] = acc;
        __syncthreads();
        if (tid == 0) {
            float tot = (sw[0] + sw[1]) + (sw[2] + sw[3]);
            int so = 0;
            for (int i = 0; i < Bn; ++i) so += olen[i];
            out[0] = tot / (float)so;
        }
    }
}

extern "C" void kernel_launch(void* const* d_in, const int* in_sizes, int n_in,
                              void* d_out, int out_size, void* d_ws, size_t ws_size,
                              hipStream_t stream) {
    const float* logp = (const float*)d_in[0];
    const float* att  = (const float*)d_in[1];
    const int* tlen   = (const int*)d_in[2];
    const int* mlen   = (const int*)d_in[3];
    float* out = (float*)d_out;
    uint64_t* bits = (uint64_t*)d_ws;                            // 2 MB
    float* partial = (float*)((char*)d_ws + 2097152);            // 4 KB
    int2* ext = (int2*)((char*)d_ws + 2101248);                  // 64 KB

    // 1) mega: forward DP (in-block staging, swizzled ring, 16-deep pipeline)
    //    + fused backtrack + concurrent loss partials
    k_mega<<<32 + 1024, 256, 0, stream>>>(logp, att, tlen, mlen, bits, partial, ext);
    // 2) write full 0/1 output from extents + final loss reduce
    k_fill<<<2048, 256, 0, stream>>>(ext, partial, mlen, out);
}

// Round 11
// 167.260 us; speedup vs baseline: 1.1502x; 1.1502x over previous
//
#include <hip/hip_runtime.h>
#include <cstdint>

#define NEG (-1e12f)
constexpr int Bn = 32, Ln = 256, Tn = 2048;
constexpr int TB = Tn / 64;                 // 32 uint64 words of t-bits per text row

// d_ws layout (bytes):
//   bits    @ 0       : 32*256*32*8 = 2,097,152
//   partial @ 2097152 : 1024 floats (4 KB)
//   ext     @ 2101248 : 8192 int2  (64 KB)

// lane i <- lane (i-1)&63  (wave_ror:1) : torch-wrap neighbor for the bit compare
__device__ inline float dpp_ror1(float x) {
    int xi = __float_as_int(x);
    return __int_as_float(__builtin_amdgcn_update_dpp(xi, xi, 0x13C, 0xF, 0xF, false));
}
// lane i <- lane i-1, lane 0 <- old  (wave_shr:1) : DP 'left' input directly
__device__ inline float dpp_shr1(float x, float old) {
    return __int_as_float(__builtin_amdgcn_update_dpp(
        __float_as_int(old), __float_as_int(x), 0x138, 0xF, 0xF, false));
}

__device__ inline uint32_t lds_off(const void* p) {
    return (uint32_t)(uintptr_t)(__attribute__((address_space(3))) const void*)p;
}

// raw barrier: NO implicit counter drain (producers' global loads stay in flight)
#define BARRIER() { asm volatile("" ::: "memory"); \
                    __builtin_amdgcn_s_barrier(); \
                    asm volatile("" ::: "memory"); }

// swizzled ds_read_b128: element (t,l) at col l ^ (16*bit2(t));
// lane block byte = (16*lane) ^ (64*bit2(row)).  ROW, BUF compile-time.
#define DSRX(DST, ROW, BUF) \
    asm volatile("ds_read_b128 %0, %1 offset:%c2" \
        : "=&v"(DST) \
        : "v"((((ROW) >> 2) & 1) ? vxb : vxa), \
          "i"((BUF) * 16384 + ((ROW) & 15) * 1024));

// consume gate: 8 slots outstanding -> oldest landed; fence non-asm hoisting (rule #18)
#define W7 { asm volatile("s_waitcnt lgkmcnt(7)"); __builtin_amdgcn_sched_barrier(0); }

// r8-proven step: immediate bit extraction. S = t - 64m (1..64) compile-time.
// bit(t,l) = beta[t][(l-1)%256] > beta[t][l]  (torch wrap), position t&63, flush S==63.
#define STEPS(S, Q) { \
    float c3 = fmaxf(pv3, pv2) + (Q).w; \
    float c2 = fmaxf(pv2, pv1) + (Q).z; \
    float c1 = fmaxf(pv1, pv0) + (Q).y; \
    float c0 = fmaxf(pv0, left) + (Q).x; \
    float sv = dpp_ror1(c3); \
    left = dpp_shr1(c3, negc); \
    uint32_t e0 = __float_as_uint(c0 - sv) >> 31; \
    uint32_t e1 = __float_as_uint(c1 - c0) >> 31; \
    uint32_t e2 = __float_as_uint(c2 - c1) >> 31; \
    uint32_t e3 = __float_as_uint(c3 - c2) >> 31; \
    if (((S) & 32) == 0) { \
        a0lo |= e0 << ((S) & 31); a1lo |= e1 << ((S) & 31); \
        a2lo |= e2 << ((S) & 31); a3lo |= e3 << ((S) & 31); \
    } else { \
        a0hi |= e0 << ((S) & 31); a1hi |= e1 << ((S) & 31); \
        a2hi |= e2 << ((S) & 31); a3hi |= e3 << ((S) & 31); \
    } \
    if ((S) == 63) { \
        bb[(size_t)(4 * lane + 0) * TB + m] = ((uint64_t)a0hi << 32) | a0lo; \
        bb[(size_t)(4 * lane + 1) * TB + m] = ((uint64_t)a1hi << 32) | a1lo; \
        bb[(size_t)(4 * lane + 2) * TB + m] = ((uint64_t)a2hi << 32) | a2lo; \
        bb[(size_t)(4 * lane + 3) * TB + m] = ((uint64_t)a3hi << 32) | a3lo; \
        a0lo = a0hi = a1lo = a1hi = a2lo = a2hi = a3lo = a3hi = 0; \
    } \
    pv0 = c0; pv1 = c1; pv2 = c2; pv3 = c3; }

// 16 DP steps of chunk c = 4m+I (buffer I); 8-deep rotating slots (r8 schedule).
// Steps 1-7 reissue rows 9..15 of buf I; steps 8-16 reissue rows 0..8 of buf I+1.
// (At m=31, I=3 the buf-0 reissues read stale data: S=64 consumes garbage, never flushed.)
#define COMP16X(I) { \
    W7 STEPS(16*(I)+ 1, qq0) DSRX(qq0,  9, (I)) \
    W7 STEPS(16*(I)+ 2, qq1) DSRX(qq1, 10, (I)) \
    W7 STEPS(16*(I)+ 3, qq2) DSRX(qq2, 11, (I)) \
    W7 STEPS(16*(I)+ 4, qq3) DSRX(qq3, 12, (I)) \
    W7 STEPS(16*(I)+ 5, qq4) DSRX(qq4, 13, (I)) \
    W7 STEPS(16*(I)+ 6, qq5) DSRX(qq5, 14, (I)) \
    W7 STEPS(16*(I)+ 7, qq6) DSRX(qq6, 15, (I)) \
    W7 STEPS(16*(I)+ 8, qq7) DSRX(qq7,  0, ((I)+1)&3) \
    W7 STEPS(16*(I)+ 9, qq0) DSRX(qq0,  1, ((I)+1)&3) \
    W7 STEPS(16*(I)+10, qq1) DSRX(qq1,  2, ((I)+1)&3) \
    W7 STEPS(16*(I)+11, qq2) DSRX(qq2,  3, ((I)+1)&3) \
    W7 STEPS(16*(I)+12, qq3) DSRX(qq3,  4, ((I)+1)&3) \
    W7 STEPS(16*(I)+13, qq4) DSRX(qq4,  5, ((I)+1)&3) \
    W7 STEPS(16*(I)+14, qq5) DSRX(qq5,  6, ((I)+1)&3) \
    W7 STEPS(16*(I)+15, qq6) DSRX(qq6,  7, ((I)+1)&3) \
    W7 STEPS(16*(I)+16, qq7) DSRX(qq7,  8, ((I)+1)&3) \
    BARRIER() }

// producer reg-staged load of chunk P (t = 16P..16P+15), 6 float4 per thread
#define PLOAD(P) { \
    xh0 = *(const float4*)(pr0 + 16 * (P)); \
    xh1 = *(const float4*)(pr1 + 16 * (P)); \
    xh2 = *(const float4*)(pr2 + 16 * (P)); \
    xh3 = *(const float4*)(pr3 + 16 * (P)); \
    xh4 = *(const float4*)(pr4 + 16 * (P)); \
    if (six) xh5 = *(const float4*)(pr5 + 16 * (P)); }

#define PW1(XH, CC) { float* rq = rr + (CC); \
    rq[0] = (XH).x; rq[256] = (XH).y; rq[512] = (XH).z; rq[768] = (XH).w; }

#define PWRITE(P) { \
    float* rr = smem + ((P) & 3) * 4096; \
    PW1(xh0, c0) PW1(xh1, c1) PW1(xh2, c2) PW1(xh3, c3) PW1(xh4, c4) \
    if (six) PW1(xh5, c5) }

// ===== mega kernel: blocks 0..31 forward+staging | 32..1055 loss partials =====
__global__ void __launch_bounds__(256, 1) k_mega(
        const float* __restrict__ logp, const float* __restrict__ att,
        const int* __restrict__ ilen, const int* __restrict__ olen,
        uint64_t* __restrict__ bits, float* __restrict__ partial) {
    __shared__ __align__(16) float smem[16384];   // 64 KB: 4 ring buffers x 16 t x 256 l
    int bid = blockIdx.x, tid = threadIdx.x;

    if (bid < 32) {
        int b = bid;
        if (tid < 64) {
            // ---------------- DP consumer wave ----------------
            __builtin_amdgcn_s_setprio(1);
            int lane = tid;
            uint64_t* bb = bits + (size_t)b * (Ln * TB);
            const float negc = NEG;
            uint32_t lb = lds_off(smem) + (uint32_t)(lane * 16);
            uint32_t vxa = lb, vxb = lb ^ 64;     // swizzle base pair

            float pv0, pv1, pv2, pv3, left;
            uint32_t a0lo = 0, a0hi = 0, a1lo = 0, a1hi = 0;
            uint32_t a2lo = 0, a2hi = 0, a3lo = 0, a3hi = 0;

            // peeled t = 0: row0 = logp[b,0,0], others NEG; seed bit 0 of word 0
            {
                float lp00 = logp[(size_t)b * (Ln * Tn)];
                float n0 = (lane == 0) ? lp00 : NEG;
                float n1 = NEG, n2 = NEG, n3 = NEG;
                float sv = dpp_ror1(n3);
                a0lo |= __float_as_uint(n0 - sv) >> 31;
                a1lo |= __float_as_uint(n1 - n0) >> 31;
                a2lo |= __float_as_uint(n2 - n1) >> 31;
                a3lo |= __float_as_uint(n3 - n2) >> 31;
                left = NEG;
                pv0 = n0; pv1 = n1; pv2 = n2; pv3 = n3;
            }

            BARRIER();                             // chunks 0,1 in LDS; chunk 2 staged in regs
            float4 qq0, qq1, qq2, qq3, qq4, qq5, qq6, qq7;
            DSRX(qq0, 1, 0) DSRX(qq1, 2, 0) DSRX(qq2, 3, 0) DSRX(qq3, 4, 0)
            DSRX(qq4, 5, 0) DSRX(qq5, 6, 0) DSRX(qq6, 7, 0) DSRX(qq7, 8, 0)

            for (int m = 0; m < 32; ++m) {
                COMP16X(0) COMP16X(1) COMP16X(2) COMP16X(3)
            }
            asm volatile("s_waitcnt vmcnt(0)" ::: "memory");  // bit flushes visible
        } else {
            // -------- producer waves: stage logp -> LDS ring, transposed + swizzled --------
            int tid2 = tid - 64;                         // 0..191
            bool six = (tid2 < 64);                      // wave-uniform extra element
            const float* lpb = logp + (size_t)b * (Ln * Tn);
            int v0 = tid2, v1 = tid2 + 192, v2 = tid2 + 384,
                v3 = tid2 + 576, v4 = tid2 + 768, v5 = tid2 + 960;
            const float* pr0 = lpb + (size_t)(v0 >> 2) * Tn + 4 * (v0 & 3);
            const float* pr1 = lpb + (size_t)(v1 >> 2) * Tn + 4 * (v1 & 3);
            const float* pr2 = lpb + (size_t)(v2 >> 2) * Tn + 4 * (v2 & 3);
            const float* pr3 = lpb + (size_t)(v3 >> 2) * Tn + 4 * (v3 & 3);
            const float* pr4 = lpb + (size_t)(v4 >> 2) * Tn + 4 * (v4 & 3);
            const float* pr5 = lpb + (size_t)(v5 >> 2) * Tn + 4 * (v5 & 3);
            // col = l ^ (16*bit2(t)); bit2(t) = v&1 for this slot mapping
            int c0 = (4 * (v0 & 3)) * 256 + ((v0 >> 2) ^ ((v0 & 1) << 4));
            int c1 = (4 * (v1 & 3)) * 256 + ((v1 >> 2) ^ ((v1 & 1) << 4));
            int c2 = (4 * (v2 & 3)) * 256 + ((v2 >> 2) ^ ((v2 & 1) << 4));
            int c3 = (4 * (v3 & 3)) * 256 + ((v3 >> 2) ^ ((v3 & 1) << 4));
            int c4 = (4 * (v4 & 3)) * 256 + ((v4 >> 2) ^ ((v4 & 1) << 4));
            int c5 = (4 * (v5 & 3)) * 256 + ((v5 >> 2) ^ ((v5 & 1) << 4));
            float4 xh0, xh1, xh2, xh3, xh4, xh5;

            PLOAD(0) PWRITE(0)                 // prologue: chunks 0,1 in LDS; chunk 2 in regs
            PLOAD(1) PWRITE(1)
            PLOAD(2)
            asm volatile("s_waitcnt lgkmcnt(0)" ::: "memory");
            BARRIER();

            for (int k = 0; k < 128; ++k) {
                if (k <= 125) PWRITE(k + 2)    // write chunk staged last iteration
                if (k <= 124) PLOAD(k + 3)     // loads span the barrier (raw s_barrier)
                asm volatile("s_waitcnt lgkmcnt(0)" ::: "memory");
                BARRIER();
            }
        }
    } else {
        // ---------------- guided-attention loss partials (independent blocks) ----------------
        const int N4 = Bn * Tn * Ln / 4;
        int j = bid - 32;
        int idx = j * 256 + tid;
        int stride = 1024 * 256;
        float acc = 0.f;
        for (int v = idx; v < N4; v += stride) {
            int flat = v << 2;                   // att is (B, T, L)
            int b  = flat >> 19;
            int t  = (flat >> 8) & (Tn - 1);
            int l0 = flat & (Ln - 1);
            int ili = ilen[b];
            int oli = olen[b];
            if (t >= oli) continue;
            float il = (float)ili, ol = (float)oli;
            float tf = (float)t / ol;
            float4 a = reinterpret_cast<const float4*>(att)[v];
            #pragma unroll
            for (int c = 0; c < 4; ++c) {
                int l = l0 + c;
                float av = (c == 0) ? a.x : (c == 1) ? a.y : (c == 2) ? a.z : a.w;
                if (l < ili) {
                    float d = (float)l / il - tf;
                    acc += (1.f - __expf(-d * d * 3.125f)) * av;
                }
            }
        }
        for (int off = 32; off > 0; off >>= 1) acc += __shfl_down(acc, off, 64);
        float* sw = smem;
        if ((tid & 63) == 0) sw[tid >> 6] = acc;
        __syncthreads();
        if (tid == 0) partial[j] = (sw[0] + sw[1]) + (sw[2] + sw[3]);
    }
}

// ---------------- backtrack: 256-thr staging, 4-deep window walk -> extents ----------------
__global__ void __launch_bounds__(256) k_backtrack(const uint64_t* __restrict__ bits,
                                                   const int* __restrict__ ilen,
                                                   const int* __restrict__ olen,
                                                   int2* __restrict__ ext) {
    __shared__ uint64_t sb[Ln * TB];   // 64 KB
    int b = blockIdx.x, tid = threadIdx.x;
    ext[b * Ln + tid] = make_int2(1, 0);          // init extents to empty
    const ulonglong2* g = (const ulonglong2*)(bits + (size_t)b * (Ln * TB));
    ulonglong2* s2 = (ulonglong2*)sb;
    #pragma unroll
    for (int i = 0; i < 16; ++i) s2[i * 256 + tid] = g[i * 256 + tid];
    __syncthreads();
    if (tid != 0) return;

    int tl = ilen[b], ml = olen[b];
    int2* eb = ext + b * Ln;
    int r = tl - 1, hi = ml - 1, p = ml - 2;
    if (p < 0) { eb[r] = make_int2(0, hi); return; }
    int c = p >> 6;
    uint64_t w0 = sb[r * TB + c];
    uint64_t w1 = sb[(r > 0 ? r - 1 : 0) * TB + c];
    uint64_t w2 = sb[(r > 1 ? r - 2 : 0) * TB + c];
    uint64_t w3 = sb[(r > 2 ? r - 3 : 0) * TB + c];
    int vd = 3;
    while (true) {
        int pb = p & 63;
        uint64_t mask = (pb == 63) ? ~0ull : ((1ull << (pb + 1)) - 1ull);
        uint64_t mm = w0 & mask;
        if (mm == 0) {
            p = (p & ~63) - 1;
            if (p < 0) { eb[r] = make_int2(0, hi); break; }
            c = p >> 6;
            w0 = sb[r * TB + c];
            w1 = sb[(r > 0 ? r - 1 : 0) * TB + c];
            w2 = sb[(r > 1 ? r - 2 : 0) * TB + c];
            w3 = sb[(r > 2 ? r - 3 : 0) * TB + c];
            vd = 3;
        } else {
            int q = 63 - __builtin_clzll(mm);
            int tq = (p & ~63) + q;
            eb[r] = make_int2(tq + 1, hi);
            r -= 1;
            if (r < 0) break;                   // saturation: remaining columns zero
            hi = tq;
            p = tq - 1;
            if (p < 0) { eb[r] = make_int2(0, hi); break; }
            w0 = w1; w1 = w2; w2 = w3; vd -= 1;
            int nc = p >> 6;
            if (nc != c || vd == 0) {
                c = nc;
                w0 = sb[r * TB + c];
                w1 = sb[(r > 0 ? r - 1 : 0) * TB + c];
                w2 = sb[(r > 1 ? r - 2 : 0) * TB + c];
                w3 = sb[(r > 2 ? r - 3 : 0) * TB + c];
                vd = 3;
            }
        }
    }
}

// ---------------- aligned-float4 fill from extents + fused final loss reduce ----------------
__global__ void k_fill(const int2* __restrict__ ext, const float* __restrict__ partial,
                       const int* __restrict__ olen, float* __restrict__ out) {
    const int NG = (Bn * Ln * Tn) / 4;          // 4,194,304 aligned float4 groups
    int idx = blockIdx.x * blockDim.x + threadIdx.x;
    int stride = gridDim.x * blockDim.x;
    for (int i = idx; i < NG; i += stride) {
        if (i == 0) {
            int2 e = ext[0];                     // out[1..3] = align f=0..2 (row 0)
            out[1] = (0 >= e.x && 0 <= e.y) ? 1.f : 0.f;
            out[2] = (1 >= e.x && 1 <= e.y) ? 1.f : 0.f;
            out[3] = (2 >= e.x && 2 <= e.y) ? 1.f : 0.f;
            int2 el = ext[Bn * Ln - 1];          // last element: row 8191, t=2047
            out[(size_t)Bn * Ln * Tn] = (2047 >= el.x && 2047 <= el.y) ? 1.f : 0.f;
            continue;
        }
        int f0 = 4 * i - 1;                      // align flat index of out[4i]
        int r0 = f0 >> 11;
        int t0 = f0 & 2047;
        int2 e0 = ext[r0];
        float4 v;
        if (t0 != 2047) {                        // all 4 in row r0
            v.x = (t0     >= e0.x && t0     <= e0.y) ? 1.f : 0.f;
            v.y = (t0 + 1 >= e0.x && t0 + 1 <= e0.y) ? 1.f : 0.f;
            v.z = (t0 + 2 >= e0.x && t0 + 2 <= e0.y) ? 1.f : 0.f;
            v.w = (t0 + 3 >= e0.x && t0 + 3 <= e0.y) ? 1.f : 0.f;
        } else {                                 // crosses into row r0+1 (t=0,1,2)
            int2 e1 = ext[r0 + 1];
            v.x = (2047 >= e0.x && 2047 <= e0.y) ? 1.f : 0.f;
            v.y = (0 >= e1.x && 0 <= e1.y) ? 1.f : 0.f;
            v.z = (1 >= e1.x && 1 <= e1.y) ? 1.f : 0.f;
            v.w = (2 >= e1.x && 2 <= e1.y) ? 1.f : 0.f;
        }
        *reinterpret_cast<float4*>(out + (size_t)4 * i) = v;
    }
    if (blockIdx.x == 0) {                       // fused deterministic loss reduce
        int tid = threadIdx.x;
        float acc = 0.f;
        for (int i = tid; i < 1024; i += 256) acc += partial[i];
        for (int off = 32; off > 0; off >>= 1) acc += __shfl_down(acc, off, 64);
        __shared__ float sw[4];
        if ((tid & 63) == 0) sw[tid >> 6] = acc;
        __syncthreads();
        if (tid == 0) {
            float tot = (sw[0] + sw[1]) + (sw[2] + sw[3]);
            int so = 0;
            for (int i = 0; i < Bn; ++i) so += olen[i];
            out[0] = tot / (float)so;
        }
    }
}

extern "C" void kernel_launch(void* const* d_in, const int* in_sizes, int n_in,
                              void* d_out, int out_size, void* d_ws, size_t ws_size,
                              hipStream_t stream) {
    const float* logp = (const float*)d_in[0];
    const float* att  = (const float*)d_in[1];
    const int* tlen   = (const int*)d_in[2];
    const int* mlen   = (const int*)d_in[3];
    float* out = (float*)d_out;
    uint64_t* bits = (uint64_t*)d_ws;                            // 2 MB
    float* partial = (float*)((char*)d_ws + 2097152);            // 4 KB
    int2* ext = (int2*)((char*)d_ws + 2101248);                  // 64 KB

    // 1) mega: forward DP (in-block staging, swizzled ring, 8-deep pipeline,
    //    r8-proven STEPS) + concurrent loss partials
    k_mega<<<32 + 1024, 256, 0, stream>>>(logp, att, tlen, mlen, bits, partial);
    // 2) backtrack -> per-row run extents
    k_backtrack<<<Bn, 256, 0, stream>>>(bits, tlen, mlen, ext);
    // 3) write full 0/1 output from extents + final loss reduce
    k_fill<<<2048, 256, 0, stream>>>(ext, partial, mlen, out);
}

// Round 12
// 164.231 us; speedup vs baseline: 1.1714x; 1.0184x over previous
//
#include <hip/hip_runtime.h>
#include <cstdint>

#define NEG (-1e12f)
constexpr int Bn = 32, Ln = 256, Tn = 2048;
constexpr int TB = Tn / 64;                 // 32 uint64 words of t-bits per text row

// d_ws layout (bytes):
//   bits    @ 0       : 32*256*32*8 = 2,097,152
//   partial @ 2097152 : 1024 floats (4 KB)
//   ext     @ 2101248 : 8192 int2  (64 KB)

// lane i <- lane (i-1)&63  (wave_ror:1) : torch-wrap neighbor for the bit compare
__device__ inline float dpp_ror1(float x) {
    int xi = __float_as_int(x);
    return __int_as_float(__builtin_amdgcn_update_dpp(xi, xi, 0x13C, 0xF, 0xF, false));
}

__device__ inline uint32_t lds_off(const void* p) {
    return (uint32_t)(uintptr_t)(__attribute__((address_space(3))) const void*)p;
}

// raw barrier: NO implicit counter drain (producers' global loads stay in flight)
#define BARRIER() { asm volatile("" ::: "memory"); \
                    __builtin_amdgcn_s_barrier(); \
                    asm volatile("" ::: "memory"); }

// swizzled ds_read_b128: element (t,l) at col l ^ (16*bit2(t));
// lane block byte = (16*lane) ^ (64*bit2(row)).  ROW, BUF compile-time.
#define DSRX(DST, ROW, BUF) \
    asm volatile("ds_read_b128 %0, %1 offset:%c2" \
        : "=&v"(DST) \
        : "v"((((ROW) >> 2) & 1) ? vxb : vxa), \
          "i"((BUF) * 16384 + ((ROW) & 15) * 1024));

// consume gate: 8 slots outstanding -> oldest landed; fence non-asm hoisting (rule #18)
#define W7 { asm volatile("s_waitcnt lgkmcnt(7)"); __builtin_amdgcn_sched_barrier(0); }

// Partial-deferral step. S = t - 64m (1..64) compile-time.
//  - e0 (the only bit needing the cross-lane sv) is extracted one step LATE:
//    e0(t-1) = sign(pv0 - svp), both live at step entry -> DPP latency hidden.
//  - left input for c0 = cndmask(svp): also a full step of slack; no 2nd DPP.
//  - e1..e3 extracted immediately from c's: BYTE-IDENTICAL to the r8-proven path
//    (accumulate at position S&63, flush word m at S==63).
//  - a0 accumulates at position (S-1)&63, flushes word m at S==64.
#define STEPS(S, Q) { \
    uint32_t e0 = __float_as_uint(pv0 - svp) >> 31;   /* bit(t-1, 4*lane) */ \
    float c3 = fmaxf(pv3, pv2) + (Q).w; \
    float sv = dpp_ror1(c3); \
    float c2 = fmaxf(pv2, pv1) + (Q).z; \
    float c1 = fmaxf(pv1, pv0) + (Q).y; \
    float lf = isl0 ? negc : svp; \
    float c0 = fmaxf(pv0, lf) + (Q).x; \
    uint32_t e1 = __float_as_uint(c1 - c0) >> 31; \
    uint32_t e2 = __float_as_uint(c2 - c1) >> 31; \
    uint32_t e3 = __float_as_uint(c3 - c2) >> 31; \
    if ((((S) - 1) & 32) == 0) { a0lo |= e0 << (((S) - 1) & 31); } \
    else                       { a0hi |= e0 << (((S) - 1) & 31); } \
    if (((S) & 32) == 0) { \
        a1lo |= e1 << ((S) & 31); a2lo |= e2 << ((S) & 31); a3lo |= e3 << ((S) & 31); \
    } else { \
        a1hi |= e1 << ((S) & 31); a2hi |= e2 << ((S) & 31); a3hi |= e3 << ((S) & 31); \
    } \
    if ((S) == 63) { \
        bb[(size_t)(4 * lane + 1) * TB + m] = ((uint64_t)a1hi << 32) | a1lo; \
        bb[(size_t)(4 * lane + 2) * TB + m] = ((uint64_t)a2hi << 32) | a2lo; \
        bb[(size_t)(4 * lane + 3) * TB + m] = ((uint64_t)a3hi << 32) | a3lo; \
        a1lo = a1hi = a2lo = a2hi = a3lo = a3hi = 0; \
    } \
    if ((S) == 64) { \
        bb[(size_t)(4 * lane + 0) * TB + m] = ((uint64_t)a0hi << 32) | a0lo; \
        a0lo = a0hi = 0; \
    } \
    pv0 = c0; pv1 = c1; pv2 = c2; pv3 = c3; svp = sv; }

// 16 DP steps of chunk c = 4m+I (buffer I); 8-deep rotating slots (r8 schedule).
// Steps 1-7 reissue rows 9..15 of buf I; steps 8-16 reissue rows 0..8 of buf I+1.
// (At m=31, I=3 the buf-0 reissues read stale data: S=64's c's are garbage, but its
//  e0 extraction uses S=63's pv/svp (valid) and the garbage c's are never extracted.)
#define COMP16X(I) { \
    W7 STEPS(16*(I)+ 1, qq0) DSRX(qq0,  9, (I)) \
    W7 STEPS(16*(I)+ 2, qq1) DSRX(qq1, 10, (I)) \
    W7 STEPS(16*(I)+ 3, qq2) DSRX(qq2, 11, (I)) \
    W7 STEPS(16*(I)+ 4, qq3) DSRX(qq3, 12, (I)) \
    W7 STEPS(16*(I)+ 5, qq4) DSRX(qq4, 13, (I)) \
    W7 STEPS(16*(I)+ 6, qq5) DSRX(qq5, 14, (I)) \
    W7 STEPS(16*(I)+ 7, qq6) DSRX(qq6, 15, (I)) \
    W7 STEPS(16*(I)+ 8, qq7) DSRX(qq7,  0, ((I)+1)&3) \
    W7 STEPS(16*(I)+ 9, qq0) DSRX(qq0,  1, ((I)+1)&3) \
    W7 STEPS(16*(I)+10, qq1) DSRX(qq1,  2, ((I)+1)&3) \
    W7 STEPS(16*(I)+11, qq2) DSRX(qq2,  3, ((I)+1)&3) \
    W7 STEPS(16*(I)+12, qq3) DSRX(qq3,  4, ((I)+1)&3) \
    W7 STEPS(16*(I)+13, qq4) DSRX(qq4,  5, ((I)+1)&3) \
    W7 STEPS(16*(I)+14, qq5) DSRX(qq5,  6, ((I)+1)&3) \
    W7 STEPS(16*(I)+15, qq6) DSRX(qq6,  7, ((I)+1)&3) \
    W7 STEPS(16*(I)+16, qq7) DSRX(qq7,  8, ((I)+1)&3) \
    BARRIER() }

// producer reg-staged load of chunk P (t = 16P..16P+15), 6 float4 per thread
#define PLOAD(P) { \
    xh0 = *(const float4*)(pr0 + 16 * (P)); \
    xh1 = *(const float4*)(pr1 + 16 * (P)); \
    xh2 = *(const float4*)(pr2 + 16 * (P)); \
    xh3 = *(const float4*)(pr3 + 16 * (P)); \
    xh4 = *(const float4*)(pr4 + 16 * (P)); \
    if (six) xh5 = *(const float4*)(pr5 + 16 * (P)); }

#define PW1(XH, CC) { float* rq = rr + (CC); \
    rq[0] = (XH).x; rq[256] = (XH).y; rq[512] = (XH).z; rq[768] = (XH).w; }

#define PWRITE(P) { \
    float* rr = smem + ((P) & 3) * 4096; \
    PW1(xh0, c0) PW1(xh1, c1) PW1(xh2, c2) PW1(xh3, c3) PW1(xh4, c4) \
    if (six) PW1(xh5, c5) }

// ===== mega kernel: blocks 0..31 forward+staging | 32..1055 loss partials =====
__global__ void __launch_bounds__(256, 1) k_mega(
        const float* __restrict__ logp, const float* __restrict__ att,
        const int* __restrict__ ilen, const int* __restrict__ olen,
        uint64_t* __restrict__ bits, float* __restrict__ partial) {
    __shared__ __align__(16) float smem[16384];   // 64 KB: 4 ring buffers x 16 t x 256 l
    int bid = blockIdx.x, tid = threadIdx.x;

    if (bid < 32) {
        int b = bid;
        if (tid < 64) {
            // ---------------- DP consumer wave ----------------
            __builtin_amdgcn_s_setprio(1);
            int lane = tid;
            bool isl0 = (lane == 0);
            uint64_t* bb = bits + (size_t)b * (Ln * TB);
            const float negc = NEG;
            uint32_t lb = lds_off(smem) + (uint32_t)(lane * 16);
            uint32_t vxa = lb, vxb = lb ^ 64;     // swizzle base pair

            float pv0, pv1, pv2, pv3, svp;
            uint32_t a0lo = 0, a0hi = 0, a1lo = 0, a1hi = 0;
            uint32_t a2lo = 0, a2hi = 0, a3lo = 0, a3hi = 0;

            // peeled t = 0: row0 = logp[b,0,0], others NEG.
            // Rows 1..3 of t=0: immediate extraction (r8 path); row 0's bit comes at S=1.
            {
                float lp00 = logp[(size_t)b * (Ln * Tn)];
                pv0 = isl0 ? lp00 : NEG;
                pv1 = NEG; pv2 = NEG; pv3 = NEG;
                svp = dpp_ror1(pv3);               // all NEG
                a1lo |= __float_as_uint(pv1 - pv0) >> 31;
                a2lo |= __float_as_uint(pv2 - pv1) >> 31;
                a3lo |= __float_as_uint(pv3 - pv2) >> 31;
            }

            BARRIER();                             // chunks 0,1 in LDS; chunk 2 staged in regs
            float4 qq0, qq1, qq2, qq3, qq4, qq5, qq6, qq7;
            DSRX(qq0, 1, 0) DSRX(qq1, 2, 0) DSRX(qq2, 3, 0) DSRX(qq3, 4, 0)
            DSRX(qq4, 5, 0) DSRX(qq5, 6, 0) DSRX(qq6, 7, 0) DSRX(qq7, 8, 0)

            for (int m = 0; m < 32; ++m) {
                COMP16X(0) COMP16X(1) COMP16X(2) COMP16X(3)
            }
            asm volatile("s_waitcnt vmcnt(0)" ::: "memory");  // bit flushes visible
        } else {
            // -------- producer waves: stage logp -> LDS ring, transposed + swizzled --------
            int tid2 = tid - 64;                         // 0..191
            bool six = (tid2 < 64);                      // wave-uniform extra element
            const float* lpb = logp + (size_t)b * (Ln * Tn);
            int v0 = tid2, v1 = tid2 + 192, v2 = tid2 + 384,
                v3 = tid2 + 576, v4 = tid2 + 768, v5 = tid2 + 960;
            const float* pr0 = lpb + (size_t)(v0 >> 2) * Tn + 4 * (v0 & 3);
            const float* pr1 = lpb + (size_t)(v1 >> 2) * Tn + 4 * (v1 & 3);
            const float* pr2 = lpb + (size_t)(v2 >> 2) * Tn + 4 * (v2 & 3);
            const float* pr3 = lpb + (size_t)(v3 >> 2) * Tn + 4 * (v3 & 3);
            const float* pr4 = lpb + (size_t)(v4 >> 2) * Tn + 4 * (v4 & 3);
            const float* pr5 = lpb + (size_t)(v5 >> 2) * Tn + 4 * (v5 & 3);
            // col = l ^ (16*bit2(t)); bit2(t) = v&1 for this slot mapping
            int c0 = (4 * (v0 & 3)) * 256 + ((v0 >> 2) ^ ((v0 & 1) << 4));
            int c1 = (4 * (v1 & 3)) * 256 + ((v1 >> 2) ^ ((v1 & 1) << 4));
            int c2 = (4 * (v2 & 3)) * 256 + ((v2 >> 2) ^ ((v2 & 1) << 4));
            int c3 = (4 * (v3 & 3)) * 256 + ((v3 >> 2) ^ ((v3 & 1) << 4));
            int c4 = (4 * (v4 & 3)) * 256 + ((v4 >> 2) ^ ((v4 & 1) << 4));
            int c5 = (4 * (v5 & 3)) * 256 + ((v5 >> 2) ^ ((v5 & 1) << 4));
            float4 xh0, xh1, xh2, xh3, xh4, xh5;

            PLOAD(0) PWRITE(0)                 // prologue: chunks 0,1 in LDS; chunk 2 in regs
            PLOAD(1) PWRITE(1)
            PLOAD(2)
            asm volatile("s_waitcnt lgkmcnt(0)" ::: "memory");
            BARRIER();

            for (int k = 0; k < 128; ++k) {
                if (k <= 125) PWRITE(k + 2)    // write chunk staged last iteration
                if (k <= 124) PLOAD(k + 3)     // loads span the barrier (raw s_barrier)
                asm volatile("s_waitcnt lgkmcnt(0)" ::: "memory");
                BARRIER();
            }
        }
    } else {
        // ---------------- guided-attention loss partials (independent blocks) ----------------
        const int N4 = Bn * Tn * Ln / 4;
        int j = bid - 32;
        int idx = j * 256 + tid;
        int stride = 1024 * 256;
        float acc = 0.f;
        for (int v = idx; v < N4; v += stride) {
            int flat = v << 2;                   // att is (B, T, L)
            int b  = flat >> 19;
            int t  = (flat >> 8) & (Tn - 1);
            int l0 = flat & (Ln - 1);
            int ili = ilen[b];
            int oli = olen[b];
            if (t >= oli) continue;
            float il = (float)ili, ol = (float)oli;
            float tf = (float)t / ol;
            float4 a = reinterpret_cast<const float4*>(att)[v];
            #pragma unroll
            for (int c = 0; c < 4; ++c) {
                int l = l0 + c;
                float av = (c == 0) ? a.x : (c == 1) ? a.y : (c == 2) ? a.z : a.w;
                if (l < ili) {
                    float d = (float)l / il - tf;
                    acc += (1.f - __expf(-d * d * 3.125f)) * av;
                }
            }
        }
        for (int off = 32; off > 0; off >>= 1) acc += __shfl_down(acc, off, 64);
        float* sw = smem;
        if ((tid & 63) == 0) sw[tid >> 6] = acc;
        __syncthreads();
        if (tid == 0) partial[j] = (sw[0] + sw[1]) + (sw[2] + sw[3]);
    }
}

// ---------------- backtrack: 256-thr staging, 4-deep window walk -> extents ----------------
__global__ void __launch_bounds__(256) k_backtrack(const uint64_t* __restrict__ bits,
                                                   const int* __restrict__ ilen,
                                                   const int* __restrict__ olen,
                                                   int2* __restrict__ ext) {
    __shared__ uint64_t sb[Ln * TB];   // 64 KB
    int b = blockIdx.x, tid = threadIdx.x;
    ext[b * Ln + tid] = make_int2(1, 0);          // init extents to empty
    const ulonglong2* g = (const ulonglong2*)(bits + (size_t)b * (Ln * TB));
    ulonglong2* s2 = (ulonglong2*)sb;
    #pragma unroll
    for (int i = 0; i < 16; ++i) s2[i * 256 + tid] = g[i * 256 + tid];
    __syncthreads();
    if (tid != 0) return;

    int tl = ilen[b], ml = olen[b];
    int2* eb = ext + b * Ln;
    int r = tl - 1, hi = ml - 1, p = ml - 2;
    if (p < 0) { eb[r] = make_int2(0, hi); return; }
    int c = p >> 6;
    uint64_t w0 = sb[r * TB + c];
    uint64_t w1 = sb[(r > 0 ? r - 1 : 0) * TB + c];
    uint64_t w2 = sb[(r > 1 ? r - 2 : 0) * TB + c];
    uint64_t w3 = sb[(r > 2 ? r - 3 : 0) * TB + c];
    int vd = 3;
    while (true) {
        int pb = p & 63;
        uint64_t mask = (pb == 63) ? ~0ull : ((1ull << (pb + 1)) - 1ull);
        uint64_t mm = w0 & mask;
        if (mm == 0) {
            p = (p & ~63) - 1;
            if (p < 0) { eb[r] = make_int2(0, hi); break; }
            c = p >> 6;
            w0 = sb[r * TB + c];
            w1 = sb[(r > 0 ? r - 1 : 0) * TB + c];
            w2 = sb[(r > 1 ? r - 2 : 0) * TB + c];
            w3 = sb[(r > 2 ? r - 3 : 0) * TB + c];
            vd = 3;
        } else {
            int q = 63 - __builtin_clzll(mm);
            int tq = (p & ~63) + q;
            eb[r] = make_int2(tq + 1, hi);
            r -= 1;
            if (r < 0) break;                   // saturation: remaining columns zero
            hi = tq;
            p = tq - 1;
            if (p < 0) { eb[r] = make_int2(0, hi); break; }
            w0 = w1; w1 = w2; w2 = w3; vd -= 1;
            int nc = p >> 6;
            if (nc != c || vd == 0) {
                c = nc;
                w0 = sb[r * TB + c];
                w1 = sb[(r > 0 ? r - 1 : 0) * TB + c];
                w2 = sb[(r > 1 ? r - 2 : 0) * TB + c];
                w3 = sb[(r > 2 ? r - 3 : 0) * TB + c];
                vd = 3;
            }
        }
    }
}

// ---------------- aligned-float4 fill from extents + fused final loss reduce ----------------
__global__ void k_fill(const int2* __restrict__ ext, const float* __restrict__ partial,
                       const int* __restrict__ olen, float* __restrict__ out) {
    const int NG = (Bn * Ln * Tn) / 4;          // 4,194,304 aligned float4 groups
    int idx = blockIdx.x * blockDim.x + threadIdx.x;
    int stride = gridDim.x * blockDim.x;
    for (int i = idx; i < NG; i += stride) {
        if (i == 0) {
            int2 e = ext[0];                     // out[1..3] = align f=0..2 (row 0)
            out[1] = (0 >= e.x && 0 <= e.y) ? 1.f : 0.f;
            out[2] = (1 >= e.x && 1 <= e.y) ? 1.f : 0.f;
            out[3] = (2 >= e.x && 2 <= e.y) ? 1.f : 0.f;
            int2 el = ext[Bn * Ln - 1];          // last element: row 8191, t=2047
            out[(size_t)Bn * Ln * Tn] = (2047 >= el.x && 2047 <= el.y) ? 1.f : 0.f;
            continue;
        }
        int f0 = 4 * i - 1;                      // align flat index of out[4i]
        int r0 = f0 >> 11;
        int t0 = f0 & 2047;
        int2 e0 = ext[r0];
        float4 v;
        if (t0 != 2047) {                        // all 4 in row r0
            v.x = (t0     >= e0.x && t0     <= e0.y) ? 1.f : 0.f;
            v.y = (t0 + 1 >= e0.x && t0 + 1 <= e0.y) ? 1.f : 0.f;
            v.z = (t0 + 2 >= e0.x && t0 + 2 <= e0.y) ? 1.f : 0.f;
            v.w = (t0 + 3 >= e0.x && t0 + 3 <= e0.y) ? 1.f : 0.f;
        } else {                                 // crosses into row r0+1 (t=0,1,2)
            int2 e1 = ext[r0 + 1];
            v.x = (2047 >= e0.x && 2047 <= e0.y) ? 1.f : 0.f;
            v.y = (0 >= e1.x && 0 <= e1.y) ? 1.f : 0.f;
            v.z = (1 >= e1.x && 1 <= e1.y) ? 1.f : 0.f;
            v.w = (2 >= e1.x && 2 <= e1.y) ? 1.f : 0.f;
        }
        *reinterpret_cast<float4*>(out + (size_t)4 * i) = v;
    }
    if (blockIdx.x == 0) {                       // fused deterministic loss reduce
        int tid = threadIdx.x;
        float acc = 0.f;
        for (int i = tid; i < 1024; i += 256) acc += partial[i];
        for (int off = 32; off > 0; off >>= 1) acc += __shfl_down(acc, off, 64);
        __shared__ float sw[4];
        if ((tid & 63) == 0) sw[tid >> 6] = acc;
        __syncthreads();
        if (tid == 0) {
            float tot = (sw[0] + sw[1]) + (sw[2] + sw[3]);
            int so = 0;
            for (int i = 0; i < Bn; ++i) so += olen[i];
            out[0] = tot / (float)so;
        }
    }
}

extern "C" void kernel_launch(void* const* d_in, const int* in_sizes, int n_in,
                              void* d_out, int out_size, void* d_ws, size_t ws_size,
                              hipStream_t stream) {
    const float* logp = (const float*)d_in[0];
    const float* att  = (const float*)d_in[1];
    const int* tlen   = (const int*)d_in[2];
    const int* mlen   = (const int*)d_in[3];
    float* out = (float*)d_out;
    uint64_t* bits = (uint64_t*)d_ws;                            // 2 MB
    float* partial = (float*)((char*)d_ws + 2097152);            // 4 KB
    int2* ext = (int2*)((char*)d_ws + 2101248);                  // 64 KB

    // 1) mega: forward DP (partial-deferral STEPS: DPP off the critical path)
    //    + concurrent loss partials
    k_mega<<<32 + 1024, 256, 0, stream>>>(logp, att, tlen, mlen, bits, partial);
    // 2) backtrack -> per-row run extents
    k_backtrack<<<Bn, 256, 0, stream>>>(bits, tlen, mlen, ext);
    // 3) write full 0/1 output from extents + final loss reduce
    k_fill<<<2048, 256, 0, stream>>>(ext, partial, mlen, out);
}

// Round 13
// 152.365 us; speedup vs baseline: 1.2627x; 1.0779x over previous
//
#include <hip/hip_runtime.h>
#include <cstdint>

#define NEG (-1e12f)
constexpr int Bn = 32, Ln = 256, Tn = 2048;
constexpr int TB = Tn / 64;                 // 32 uint64 words of t-bits per text row

// d_ws layout (bytes):
//   bits    @ 0       : 32*256*32*8 = 2,097,152
//   partial @ 2097152 : 1024 floats (4 KB)
//   ext     @ 2101248 : 8192 int2  (64 KB)

// lane i <- lane (i-1)&63  (wave_ror:1) : torch-wrap neighbor for the bit compare
__device__ inline float dpp_ror1(float x) {
    int xi = __float_as_int(x);
    return __int_as_float(__builtin_amdgcn_update_dpp(xi, xi, 0x13C, 0xF, 0xF, false));
}

__device__ inline uint32_t lds_off(const void* p) {
    return (uint32_t)(uintptr_t)(__attribute__((address_space(3))) const void*)p;
}

// raw barrier: NO implicit counter drain (producers' global loads stay in flight)
#define BARRIER() { asm volatile("" ::: "memory"); \
                    __builtin_amdgcn_s_barrier(); \
                    asm volatile("" ::: "memory"); }

// swizzled ds_read_b128: element (t,l) at col l ^ (16*bit2(t));
// lane block byte = (16*lane) ^ (64*bit2(row)).  ROW, BUF compile-time.
#define DSRX(DST, ROW, BUF) \
    asm volatile("ds_read_b128 %0, %1 offset:%c2" \
        : "=&v"(DST) \
        : "v"((((ROW) >> 2) & 1) ? vxb : vxa), \
          "i"((BUF) * 16384 + ((ROW) & 15) * 1024));

// coarse consume gate: once per 4 steps. 8 outstanding -> wait until the 4 oldest
// (the group about to be consumed, issued >=12 steps ago) have landed.
// sched_barrier keeps the group's consumers below the wait (rule #18), but gives
// the scheduler a 4-step window to fill VALU dependency stalls (1 wave/SIMD).
#define W4 { asm volatile("s_waitcnt lgkmcnt(4)"); __builtin_amdgcn_sched_barrier(0); }

// r12-proven partial-deferral step. S = t - 64m (1..64) compile-time.
//  - e0 (needs cross-lane sv) extracted one step late from pv0/svp (DPP hidden)
//  - left = cndmask(svp); no second DPP
//  - e1..e3 immediate (r8 path), flush at S==63; a0 flushes at S==64, pos (S-1)&63
#define STEPS(S, Q) { \
    uint32_t e0 = __float_as_uint(pv0 - svp) >> 31;   /* bit(t-1, 4*lane) */ \
    float c3 = fmaxf(pv3, pv2) + (Q).w; \
    float sv = dpp_ror1(c3); \
    float c2 = fmaxf(pv2, pv1) + (Q).z; \
    float c1 = fmaxf(pv1, pv0) + (Q).y; \
    float lf = isl0 ? negc : svp; \
    float c0 = fmaxf(pv0, lf) + (Q).x; \
    uint32_t e1 = __float_as_uint(c1 - c0) >> 31; \
    uint32_t e2 = __float_as_uint(c2 - c1) >> 31; \
    uint32_t e3 = __float_as_uint(c3 - c2) >> 31; \
    if ((((S) - 1) & 32) == 0) { a0lo |= e0 << (((S) - 1) & 31); } \
    else                       { a0hi |= e0 << (((S) - 1) & 31); } \
    if (((S) & 32) == 0) { \
        a1lo |= e1 << ((S) & 31); a2lo |= e2 << ((S) & 31); a3lo |= e3 << ((S) & 31); \
    } else { \
        a1hi |= e1 << ((S) & 31); a2hi |= e2 << ((S) & 31); a3hi |= e3 << ((S) & 31); \
    } \
    if ((S) == 63) { \
        bb[(size_t)(4 * lane + 1) * TB + m] = ((uint64_t)a1hi << 32) | a1lo; \
        bb[(size_t)(4 * lane + 2) * TB + m] = ((uint64_t)a2hi << 32) | a2lo; \
        bb[(size_t)(4 * lane + 3) * TB + m] = ((uint64_t)a3hi << 32) | a3lo; \
        a1lo = a1hi = a2lo = a2hi = a3lo = a3hi = 0; \
    } \
    if ((S) == 64) { \
        bb[(size_t)(4 * lane + 0) * TB + m] = ((uint64_t)a0hi << 32) | a0lo; \
        a0lo = a0hi = 0; \
    } \
    pv0 = c0; pv1 = c1; pv2 = c2; pv3 = c3; svp = sv; }

// 16 DP steps of chunk c = 4m+I (buffer I); 8 slots, 4-step groups.
// Group: W4 -> consume 4 slots -> reissue those 4 slots for rows 12..15 later.
// Reads of buf I+1 rows 0..8 are safe pre-barrier (written one chunk ago).
#define COMP16X(I) { \
    W4 \
    STEPS(16*(I)+ 1, qq0) STEPS(16*(I)+ 2, qq1) STEPS(16*(I)+ 3, qq2) STEPS(16*(I)+ 4, qq3) \
    DSRX(qq0,  9, (I)) DSRX(qq1, 10, (I)) DSRX(qq2, 11, (I)) DSRX(qq3, 12, (I)) \
    W4 \
    STEPS(16*(I)+ 5, qq4) STEPS(16*(I)+ 6, qq5) STEPS(16*(I)+ 7, qq6) STEPS(16*(I)+ 8, qq7) \
    DSRX(qq4, 13, (I)) DSRX(qq5, 14, (I)) DSRX(qq6, 15, (I)) DSRX(qq7,  0, ((I)+1)&3) \
    W4 \
    STEPS(16*(I)+ 9, qq0) STEPS(16*(I)+10, qq1) STEPS(16*(I)+11, qq2) STEPS(16*(I)+12, qq3) \
    DSRX(qq0,  1, ((I)+1)&3) DSRX(qq1,  2, ((I)+1)&3) DSRX(qq2,  3, ((I)+1)&3) DSRX(qq3,  4, ((I)+1)&3) \
    W4 \
    STEPS(16*(I)+13, qq4) STEPS(16*(I)+14, qq5) STEPS(16*(I)+15, qq6) STEPS(16*(I)+16, qq7) \
    DSRX(qq4,  5, ((I)+1)&3) DSRX(qq5,  6, ((I)+1)&3) DSRX(qq6,  7, ((I)+1)&3) DSRX(qq7,  8, ((I)+1)&3) \
    BARRIER() }

// producer reg-staged load of chunk P (t = 16P..16P+15), 6 float4 per thread
#define PLOAD(P) { \
    xh0 = *(const float4*)(pr0 + 16 * (P)); \
    xh1 = *(const float4*)(pr1 + 16 * (P)); \
    xh2 = *(const float4*)(pr2 + 16 * (P)); \
    xh3 = *(const float4*)(pr3 + 16 * (P)); \
    xh4 = *(const float4*)(pr4 + 16 * (P)); \
    if (six) xh5 = *(const float4*)(pr5 + 16 * (P)); }

#define PW1(XH, CC) { float* rq = rr + (CC); \
    rq[0] = (XH).x; rq[256] = (XH).y; rq[512] = (XH).z; rq[768] = (XH).w; }

#define PWRITE(P) { \
    float* rr = smem + ((P) & 3) * 4096; \
    PW1(xh0, c0) PW1(xh1, c1) PW1(xh2, c2) PW1(xh3, c3) PW1(xh4, c4) \
    if (six) PW1(xh5, c5) }

// ===== mega kernel: blocks 0..31 forward+staging | 32..1055 loss partials =====
__global__ void __launch_bounds__(256, 1) k_mega(
        const float* __restrict__ logp, const float* __restrict__ att,
        const int* __restrict__ ilen, const int* __restrict__ olen,
        uint64_t* __restrict__ bits, float* __restrict__ partial) {
    __shared__ __align__(16) float smem[16384];   // 64 KB: 4 ring buffers x 16 t x 256 l
    int bid = blockIdx.x, tid = threadIdx.x;

    if (bid < 32) {
        int b = bid;
        if (tid < 64) {
            // ---------------- DP consumer wave ----------------
            __builtin_amdgcn_s_setprio(1);
            int lane = tid;
            bool isl0 = (lane == 0);
            uint64_t* bb = bits + (size_t)b * (Ln * TB);
            const float negc = NEG;
            uint32_t lb = lds_off(smem) + (uint32_t)(lane * 16);
            uint32_t vxa = lb, vxb = lb ^ 64;     // swizzle base pair

            float pv0, pv1, pv2, pv3, svp;
            uint32_t a0lo = 0, a0hi = 0, a1lo = 0, a1hi = 0;
            uint32_t a2lo = 0, a2hi = 0, a3lo = 0, a3hi = 0;

            // peeled t = 0: row0 = logp[b,0,0], others NEG.
            // Rows 1..3 of t=0: immediate extraction; row 0's bit comes at S=1.
            {
                float lp00 = logp[(size_t)b * (Ln * Tn)];
                pv0 = isl0 ? lp00 : NEG;
                pv1 = NEG; pv2 = NEG; pv3 = NEG;
                svp = dpp_ror1(pv3);               // all NEG
                a1lo |= __float_as_uint(pv1 - pv0) >> 31;
                a2lo |= __float_as_uint(pv2 - pv1) >> 31;
                a3lo |= __float_as_uint(pv3 - pv2) >> 31;
            }

            BARRIER();                             // chunks 0,1 in LDS; chunk 2 staged in regs
            float4 qq0, qq1, qq2, qq3, qq4, qq5, qq6, qq7;
            DSRX(qq0, 1, 0) DSRX(qq1, 2, 0) DSRX(qq2, 3, 0) DSRX(qq3, 4, 0)
            DSRX(qq4, 5, 0) DSRX(qq5, 6, 0) DSRX(qq6, 7, 0) DSRX(qq7, 8, 0)

            for (int m = 0; m < 32; ++m) {
                COMP16X(0) COMP16X(1) COMP16X(2) COMP16X(3)
            }
            asm volatile("s_waitcnt vmcnt(0)" ::: "memory");  // bit flushes visible
        } else {
            // -------- producer waves: stage logp -> LDS ring, transposed + swizzled --------
            int tid2 = tid - 64;                         // 0..191
            bool six = (tid2 < 64);                      // wave-uniform extra element
            const float* lpb = logp + (size_t)b * (Ln * Tn);
            int v0 = tid2, v1 = tid2 + 192, v2 = tid2 + 384,
                v3 = tid2 + 576, v4 = tid2 + 768, v5 = tid2 + 960;
            const float* pr0 = lpb + (size_t)(v0 >> 2) * Tn + 4 * (v0 & 3);
            const float* pr1 = lpb + (size_t)(v1 >> 2) * Tn + 4 * (v1 & 3);
            const float* pr2 = lpb + (size_t)(v2 >> 2) * Tn + 4 * (v2 & 3);
            const float* pr3 = lpb + (size_t)(v3 >> 2) * Tn + 4 * (v3 & 3);
            const float* pr4 = lpb + (size_t)(v4 >> 2) * Tn + 4 * (v4 & 3);
            const float* pr5 = lpb + (size_t)(v5 >> 2) * Tn + 4 * (v5 & 3);
            // col = l ^ (16*bit2(t)); bit2(t) = v&1 for this slot mapping
            int c0 = (4 * (v0 & 3)) * 256 + ((v0 >> 2) ^ ((v0 & 1) << 4));
            int c1 = (4 * (v1 & 3)) * 256 + ((v1 >> 2) ^ ((v1 & 1) << 4));
            int c2 = (4 * (v2 & 3)) * 256 + ((v2 >> 2) ^ ((v2 & 1) << 4));
            int c3 = (4 * (v3 & 3)) * 256 + ((v3 >> 2) ^ ((v3 & 1) << 4));
            int c4 = (4 * (v4 & 3)) * 256 + ((v4 >> 2) ^ ((v4 & 1) << 4));
            int c5 = (4 * (v5 & 3)) * 256 + ((v5 >> 2) ^ ((v5 & 1) << 4));
            float4 xh0, xh1, xh2, xh3, xh4, xh5;

            PLOAD(0) PWRITE(0)                 // prologue: chunks 0,1 in LDS; chunk 2 in regs
            PLOAD(1) PWRITE(1)
            PLOAD(2)
            asm volatile("s_waitcnt lgkmcnt(0)" ::: "memory");
            BARRIER();

            for (int k = 0; k < 128; ++k) {
                if (k <= 125) PWRITE(k + 2)    // write chunk staged last iteration
                if (k <= 124) PLOAD(k + 3)     // loads span the barrier (raw s_barrier)
                asm volatile("s_waitcnt lgkmcnt(0)" ::: "memory");
                BARRIER();
            }
        }
    } else {
        // ---------------- guided-attention loss partials (independent blocks) ----------------
        const int N4 = Bn * Tn * Ln / 4;
        int j = bid - 32;
        int idx = j * 256 + tid;
        int stride = 1024 * 256;
        float acc = 0.f;
        for (int v = idx; v < N4; v += stride) {
            int flat = v << 2;                   // att is (B, T, L)
            int b  = flat >> 19;
            int t  = (flat >> 8) & (Tn - 1);
            int l0 = flat & (Ln - 1);
            int ili = ilen[b];
            int oli = olen[b];
            if (t >= oli) continue;
            float il = (float)ili, ol = (float)oli;
            float tf = (float)t / ol;
            float4 a = reinterpret_cast<const float4*>(att)[v];
            #pragma unroll
            for (int c = 0; c < 4; ++c) {
                int l = l0 + c;
                float av = (c == 0) ? a.x : (c == 1) ? a.y : (c == 2) ? a.z : a.w;
                if (l < ili) {
                    float d = (float)l / il - tf;
                    acc += (1.f - __expf(-d * d * 3.125f)) * av;
                }
            }
        }
        for (int off = 32; off > 0; off >>= 1) acc += __shfl_down(acc, off, 64);
        float* sw = smem;
        if ((tid & 63) == 0) sw[tid >> 6] = acc;
        __syncthreads();
        if (tid == 0) partial[j] = (sw[0] + sw[1]) + (sw[2] + sw[3]);
    }
}

// ---------------- backtrack: 256-thr staging, 4-deep window walk -> extents ----------------
__global__ void __launch_bounds__(256) k_backtrack(const uint64_t* __restrict__ bits,
                                                   const int* __restrict__ ilen,
                                                   const int* __restrict__ olen,
                                                   int2* __restrict__ ext) {
    __shared__ uint64_t sb[Ln * TB];   // 64 KB
    int b = blockIdx.x, tid = threadIdx.x;
    ext[b * Ln + tid] = make_int2(1, 0);          // init extents to empty
    const ulonglong2* g = (const ulonglong2*)(bits + (size_t)b * (Ln * TB));
    ulonglong2* s2 = (ulonglong2*)sb;
    #pragma unroll
    for (int i = 0; i < 16; ++i) s2[i * 256 + tid] = g[i * 256 + tid];
    __syncthreads();
    if (tid != 0) return;

    int tl = ilen[b], ml = olen[b];
    int2* eb = ext + b * Ln;
    int r = tl - 1, hi = ml - 1, p = ml - 2;
    if (p < 0) { eb[r] = make_int2(0, hi); return; }
    int c = p >> 6;
    uint64_t w0 = sb[r * TB + c];
    uint64_t w1 = sb[(r > 0 ? r - 1 : 0) * TB + c];
    uint64_t w2 = sb[(r > 1 ? r - 2 : 0) * TB + c];
    uint64_t w3 = sb[(r > 2 ? r - 3 : 0) * TB + c];
    int vd = 3;
    while (true) {
        int pb = p & 63;
        uint64_t mask = (pb == 63) ? ~0ull : ((1ull << (pb + 1)) - 1ull);
        uint64_t mm = w0 & mask;
        if (mm == 0) {
            p = (p & ~63) - 1;
            if (p < 0) { eb[r] = make_int2(0, hi); break; }
            c = p >> 6;
            w0 = sb[r * TB + c];
            w1 = sb[(r > 0 ? r - 1 : 0) * TB + c];
            w2 = sb[(r > 1 ? r - 2 : 0) * TB + c];
            w3 = sb[(r > 2 ? r - 3 : 0) * TB + c];
            vd = 3;
        } else {
            int q = 63 - __builtin_clzll(mm);
            int tq = (p & ~63) + q;
            eb[r] = make_int2(tq + 1, hi);
            r -= 1;
            if (r < 0) break;                   // saturation: remaining columns zero
            hi = tq;
            p = tq - 1;
            if (p < 0) { eb[r] = make_int2(0, hi); break; }
            w0 = w1; w1 = w2; w2 = w3; vd -= 1;
            int nc = p >> 6;
            if (nc != c || vd == 0) {
                c = nc;
                w0 = sb[r * TB + c];
                w1 = sb[(r > 0 ? r - 1 : 0) * TB + c];
                w2 = sb[(r > 1 ? r - 2 : 0) * TB + c];
                w3 = sb[(r > 2 ? r - 3 : 0) * TB + c];
                vd = 3;
            }
        }
    }
}

// ---------------- aligned-float4 fill from extents + fused final loss reduce ----------------
__global__ void k_fill(const int2* __restrict__ ext, const float* __restrict__ partial,
                       const int* __restrict__ olen, float* __restrict__ out) {
    const int NG = (Bn * Ln * Tn) / 4;          // 4,194,304 aligned float4 groups
    int idx = blockIdx.x * blockDim.x + threadIdx.x;
    int stride = gridDim.x * blockDim.x;
    for (int i = idx; i < NG; i += stride) {
        if (i == 0) {
            int2 e = ext[0];                     // out[1..3] = align f=0..2 (row 0)
            out[1] = (0 >= e.x && 0 <= e.y) ? 1.f : 0.f;
            out[2] = (1 >= e.x && 1 <= e.y) ? 1.f : 0.f;
            out[3] = (2 >= e.x && 2 <= e.y) ? 1.f : 0.f;
            int2 el = ext[Bn * Ln - 1];          // last element: row 8191, t=2047
            out[(size_t)Bn * Ln * Tn] = (2047 >= el.x && 2047 <= el.y) ? 1.f : 0.f;
            continue;
        }
        int f0 = 4 * i - 1;                      // align flat index of out[4i]
        int r0 = f0 >> 11;
        int t0 = f0 & 2047;
        int2 e0 = ext[r0];
        float4 v;
        if (t0 != 2047) {                        // all 4 in row r0
            v.x = (t0     >= e0.x && t0     <= e0.y) ? 1.f : 0.f;
            v.y = (t0 + 1 >= e0.x && t0 + 1 <= e0.y) ? 1.f : 0.f;
            v.z = (t0 + 2 >= e0.x && t0 + 2 <= e0.y) ? 1.f : 0.f;
            v.w = (t0 + 3 >= e0.x && t0 + 3 <= e0.y) ? 1.f : 0.f;
        } else {                                 // crosses into row r0+1 (t=0,1,2)
            int2 e1 = ext[r0 + 1];
            v.x = (2047 >= e0.x && 2047 <= e0.y) ? 1.f : 0.f;
            v.y = (0 >= e1.x && 0 <= e1.y) ? 1.f : 0.f;
            v.z = (1 >= e1.x && 1 <= e1.y) ? 1.f : 0.f;
            v.w = (2 >= e1.x && 2 <= e1.y) ? 1.f : 0.f;
        }
        *reinterpret_cast<float4*>(out + (size_t)4 * i) = v;
    }
    if (blockIdx.x == 0) {                       // fused deterministic loss reduce
        int tid = threadIdx.x;
        float acc = 0.f;
        for (int i = tid; i < 1024; i += 256) acc += partial[i];
        for (int off = 32; off > 0; off >>= 1) acc += __shfl_down(acc, off, 64);
        __shared__ float sw[4];
        if ((tid & 63) == 0) sw[tid >> 6] = acc;
        __syncthreads();
        if (tid == 0) {
            float tot = (sw[0] + sw[1]) + (sw[2] + sw[3]);
            int so = 0;
            for (int i = 0; i < Bn; ++i) so += olen[i];
            out[0] = tot / (float)so;
        }
    }
}

extern "C" void kernel_launch(void* const* d_in, const int* in_sizes, int n_in,
                              void* d_out, int out_size, void* d_ws, size_t ws_size,
                              hipStream_t stream) {
    const float* logp = (const float*)d_in[0];
    const float* att  = (const float*)d_in[1];
    const int* tlen   = (const int*)d_in[2];
    const int* mlen   = (const int*)d_in[3];
    float* out = (float*)d_out;
    uint64_t* bits = (uint64_t*)d_ws;                            // 2 MB
    float* partial = (float*)((char*)d_ws + 2097152);            // 4 KB
    int2* ext = (int2*)((char*)d_ws + 2101248);                  // 64 KB

    // 1) mega: forward DP (coarse 4-step waitcnt windows: scheduler can fill
    //    dep stalls across steps) + concurrent loss partials
    k_mega<<<32 + 1024, 256, 0, stream>>>(logp, att, tlen, mlen, bits, partial);
    // 2) backtrack -> per-row run extents
    k_backtrack<<<Bn, 256, 0, stream>>>(bits, tlen, mlen, ext);
    // 3) write full 0/1 output from extents + final loss reduce
    k_fill<<<2048, 256, 0, stream>>>(ext, partial, mlen, out);
}

// Round 14
// 135.474 us; speedup vs baseline: 1.4201x; 1.1247x over previous
//
#include <hip/hip_runtime.h>
#include <cstdint>

#define NEG (-1e12f)
constexpr int Bn = 32, Ln = 256, Tn = 2048;
constexpr int TB = Tn / 64;                 // 32 uint64 words of t-bits per text row

// d_ws layout (bytes):
//   bits    @ 0       : 32*256*32*8 = 2,097,152
//   partial @ 2097152 : 1024 floats (4 KB)
//   ext     @ 2101248 : 8192 int2  (64 KB)

// lane i <- lane (i-1)&63  (wave_ror:1) : torch-wrap neighbor for the bit compare
__device__ inline float dpp_ror1(float x) {
    int xi = __float_as_int(x);
    return __int_as_float(__builtin_amdgcn_update_dpp(xi, xi, 0x13C, 0xF, 0xF, false));
}

__device__ inline uint32_t lds_off(const void* p) {
    return (uint32_t)(uintptr_t)(__attribute__((address_space(3))) const void*)p;
}

// raw barrier: NO implicit counter drain (producers' global loads stay in flight)
#define BARRIER() { asm volatile("" ::: "memory"); \
                    __builtin_amdgcn_s_barrier(); \
                    asm volatile("" ::: "memory"); }

// swizzled ds_read_b128: element (t,l) at col l ^ (16*bit2(t));
// lane block byte = (16*lane) ^ (64*bit2(row)).  ROW, BUF compile-time.
#define DSRX(DST, ROW, BUF) \
    asm volatile("ds_read_b128 %0, %1 offset:%c2" \
        : "=&v"(DST) \
        : "v"((((ROW) >> 2) & 1) ? vxb : vxa), \
          "i"((BUF) * 16384 + ((ROW) & 15) * 1024));

// coarse consume gate: once per 4 steps (r13-proven)
#define W4 { asm volatile("s_waitcnt lgkmcnt(4)"); __builtin_amdgcn_sched_barrier(0); }

// shift-accumulate one comparison bit: ACC = (ACC<<1) | (X > Y).
// 2 instr (cmp + addc) vs 3 for the sub/shift/or path. Bits land MSB-first;
// backtrack bit-reverses each word on load to restore t-order.
#define ABIT(ACC, X, Y) \
    asm("v_cmp_gt_f32 vcc, %1, %2\n\tv_addc_co_u32 %0, vcc, %0, %0, vcc" \
        : "+v"(ACC) : "v"(X), "v"(Y) : "vcc");

// Partial-deferral step with addc bit packing. S = t - 64m (1..64) compile-time.
//  - row0 bit (needs cross-lane sv) extracted one step late: (svp > pv0) at step S
//    covers t-1. Word m of row0 = accs S=1..64 (hi: S<=32, lo: S>=33), flush S==64.
//  - rows1..3 immediate: bit(t,4l+k) = c_{k-1} > c_k. Word m = accs {S==64 of m-1
//    (or peel for m=0)} + S=1..63 (hi: S=1..31 [+init], lo: S=32..63), flush S==63.
#define STEPS(S, Q) { \
    if ((((S) - 1) & 32) == 0) { ABIT(a0hi, svp, pv0) } else { ABIT(a0lo, svp, pv0) } \
    float c3 = fmaxf(pv3, pv2) + (Q).w; \
    float sv = dpp_ror1(c3); \
    float c2 = fmaxf(pv2, pv1) + (Q).z; \
    float c1 = fmaxf(pv1, pv0) + (Q).y; \
    float lf = isl0 ? negc : svp; \
    float c0 = fmaxf(pv0, lf) + (Q).x; \
    if (((S) & 32) == 0) { \
        ABIT(a1hi, c0, c1) ABIT(a2hi, c1, c2) ABIT(a3hi, c2, c3) \
    } else { \
        ABIT(a1lo, c0, c1) ABIT(a2lo, c1, c2) ABIT(a3lo, c2, c3) \
    } \
    if ((S) == 63) { \
        bb[(size_t)(4 * lane + 1) * TB + m] = ((uint64_t)a1hi << 32) | a1lo; \
        bb[(size_t)(4 * lane + 2) * TB + m] = ((uint64_t)a2hi << 32) | a2lo; \
        bb[(size_t)(4 * lane + 3) * TB + m] = ((uint64_t)a3hi << 32) | a3lo; \
        a1lo = a1hi = a2lo = a2hi = a3lo = a3hi = 0; \
    } \
    if ((S) == 64) { \
        bb[(size_t)(4 * lane + 0) * TB + m] = ((uint64_t)a0hi << 32) | a0lo; \
        a0lo = a0hi = 0; \
    } \
    pv0 = c0; pv1 = c1; pv2 = c2; pv3 = c3; svp = sv; }

// 16 DP steps of chunk c = 4m+I (buffer I); 8 slots, 4-step groups (r13 schedule)
#define COMP16X(I) { \
    W4 \
    STEPS(16*(I)+ 1, qq0) STEPS(16*(I)+ 2, qq1) STEPS(16*(I)+ 3, qq2) STEPS(16*(I)+ 4, qq3) \
    DSRX(qq0,  9, (I)) DSRX(qq1, 10, (I)) DSRX(qq2, 11, (I)) DSRX(qq3, 12, (I)) \
    W4 \
    STEPS(16*(I)+ 5, qq4) STEPS(16*(I)+ 6, qq5) STEPS(16*(I)+ 7, qq6) STEPS(16*(I)+ 8, qq7) \
    DSRX(qq4, 13, (I)) DSRX(qq5, 14, (I)) DSRX(qq6, 15, (I)) DSRX(qq7,  0, ((I)+1)&3) \
    W4 \
    STEPS(16*(I)+ 9, qq0) STEPS(16*(I)+10, qq1) STEPS(16*(I)+11, qq2) STEPS(16*(I)+12, qq3) \
    DSRX(qq0,  1, ((I)+1)&3) DSRX(qq1,  2, ((I)+1)&3) DSRX(qq2,  3, ((I)+1)&3) DSRX(qq3,  4, ((I)+1)&3) \
    W4 \
    STEPS(16*(I)+13, qq4) STEPS(16*(I)+14, qq5) STEPS(16*(I)+15, qq6) STEPS(16*(I)+16, qq7) \
    DSRX(qq4,  5, ((I)+1)&3) DSRX(qq5,  6, ((I)+1)&3) DSRX(qq6,  7, ((I)+1)&3) DSRX(qq7,  8, ((I)+1)&3) \
    BARRIER() }

// producer reg-staged load of chunk P (t = 16P..16P+15), 6 float4 per thread
#define PLOAD(P) { \
    xh0 = *(const float4*)(pr0 + 16 * (P)); \
    xh1 = *(const float4*)(pr1 + 16 * (P)); \
    xh2 = *(const float4*)(pr2 + 16 * (P)); \
    xh3 = *(const float4*)(pr3 + 16 * (P)); \
    xh4 = *(const float4*)(pr4 + 16 * (P)); \
    if (six) xh5 = *(const float4*)(pr5 + 16 * (P)); }

#define PW1(XH, CC) { float* rq = rr + (CC); \
    rq[0] = (XH).x; rq[256] = (XH).y; rq[512] = (XH).z; rq[768] = (XH).w; }

#define PWRITE(P) { \
    float* rr = smem + ((P) & 3) * 4096; \
    PW1(xh0, c0) PW1(xh1, c1) PW1(xh2, c2) PW1(xh3, c3) PW1(xh4, c4) \
    if (six) PW1(xh5, c5) }

// ===== mega kernel: blocks 0..31 forward+staging | 32..1055 loss partials =====
// smem = 96 KB (ring uses first 64 KB): forces 1 block/CU, so each forward block
// owns its CU's LDS pipe and SIMDs exclusively (no forward-forward or loss
// co-residency — dispatch placement no longer matters).
__global__ void __launch_bounds__(256, 1) k_mega(
        const float* __restrict__ logp, const float* __restrict__ att,
        const int* __restrict__ ilen, const int* __restrict__ olen,
        uint64_t* __restrict__ bits, float* __restrict__ partial) {
    __shared__ __align__(16) float smem[24576];   // 96 KB (ring = first 64 KB)
    int bid = blockIdx.x, tid = threadIdx.x;

    if (bid < 32) {
        int b = bid;
        if (tid < 64) {
            // ---------------- DP consumer wave ----------------
            __builtin_amdgcn_s_setprio(1);
            int lane = tid;
            bool isl0 = (lane == 0);
            uint64_t* bb = bits + (size_t)b * (Ln * TB);
            const float negc = NEG;
            uint32_t lb = lds_off(smem) + (uint32_t)(lane * 16);
            uint32_t vxa = lb, vxb = lb ^ 64;     // swizzle base pair

            float pv0, pv1, pv2, pv3, svp;
            uint32_t a0lo = 0, a0hi = 0, a1lo = 0, a1hi = 0;
            uint32_t a2lo = 0, a2hi = 0, a3lo = 0, a3hi = 0;

            // peeled t = 0: row0 = logp[b,0,0], others NEG.
            // rows1..3 t=0 bits seed the hi accumulators (first shift-in);
            // row0's t=0 bit comes via deferral at S=1.
            {
                float lp00 = logp[(size_t)b * (Ln * Tn)];
                pv0 = isl0 ? lp00 : NEG;
                pv1 = NEG; pv2 = NEG; pv3 = NEG;
                svp = dpp_ror1(pv3);               // all NEG
                a1hi = (pv0 > pv1) ? 1u : 0u;      // bit(0, 4*lane+1)
                a2hi = (pv1 > pv2) ? 1u : 0u;      // 0
                a3hi = (pv2 > pv3) ? 1u : 0u;      // 0
            }

            BARRIER();                             // chunks 0,1 in LDS; chunk 2 staged in regs
            float4 qq0, qq1, qq2, qq3, qq4, qq5, qq6, qq7;
            DSRX(qq0, 1, 0) DSRX(qq1, 2, 0) DSRX(qq2, 3, 0) DSRX(qq3, 4, 0)
            DSRX(qq4, 5, 0) DSRX(qq5, 6, 0) DSRX(qq6, 7, 0) DSRX(qq7, 8, 0)

            for (int m = 0; m < 32; ++m) {
                COMP16X(0) COMP16X(1) COMP16X(2) COMP16X(3)
            }
            asm volatile("s_waitcnt vmcnt(0)" ::: "memory");  // bit flushes visible
        } else {
            // -------- producer waves: stage logp -> LDS ring, transposed + swizzled --------
            int tid2 = tid - 64;                         // 0..191
            bool six = (tid2 < 64);                      // wave-uniform extra element
            const float* lpb = logp + (size_t)b * (Ln * Tn);
            int v0 = tid2, v1 = tid2 + 192, v2 = tid2 + 384,
                v3 = tid2 + 576, v4 = tid2 + 768, v5 = tid2 + 960;
            const float* pr0 = lpb + (size_t)(v0 >> 2) * Tn + 4 * (v0 & 3);
            const float* pr1 = lpb + (size_t)(v1 >> 2) * Tn + 4 * (v1 & 3);
            const float* pr2 = lpb + (size_t)(v2 >> 2) * Tn + 4 * (v2 & 3);
            const float* pr3 = lpb + (size_t)(v3 >> 2) * Tn + 4 * (v3 & 3);
            const float* pr4 = lpb + (size_t)(v4 >> 2) * Tn + 4 * (v4 & 3);
            const float* pr5 = lpb + (size_t)(v5 >> 2) * Tn + 4 * (v5 & 3);
            // col = l ^ (16*bit2(t)); bit2(t) = v&1 for this slot mapping
            int c0 = (4 * (v0 & 3)) * 256 + ((v0 >> 2) ^ ((v0 & 1) << 4));
            int c1 = (4 * (v1 & 3)) * 256 + ((v1 >> 2) ^ ((v1 & 1) << 4));
            int c2 = (4 * (v2 & 3)) * 256 + ((v2 >> 2) ^ ((v2 & 1) << 4));
            int c3 = (4 * (v3 & 3)) * 256 + ((v3 >> 2) ^ ((v3 & 1) << 4));
            int c4 = (4 * (v4 & 3)) * 256 + ((v4 >> 2) ^ ((v4 & 1) << 4));
            int c5 = (4 * (v5 & 3)) * 256 + ((v5 >> 2) ^ ((v5 & 1) << 4));
            float4 xh0, xh1, xh2, xh3, xh4, xh5;

            PLOAD(0) PWRITE(0)                 // prologue: chunks 0,1 in LDS; chunk 2 in regs
            PLOAD(1) PWRITE(1)
            PLOAD(2)
            asm volatile("s_waitcnt lgkmcnt(0)" ::: "memory");
            BARRIER();

            for (int k = 0; k < 128; ++k) {
                if (k <= 125) PWRITE(k + 2)    // write chunk staged last iteration
                if (k <= 124) PLOAD(k + 3)     // loads span the barrier (raw s_barrier)
                asm volatile("s_waitcnt lgkmcnt(0)" ::: "memory");
                BARRIER();
            }
        }
    } else {
        // ---------------- guided-attention loss partials (independent blocks) ----------------
        const int N4 = Bn * Tn * Ln / 4;
        int j = bid - 32;
        int idx = j * 256 + tid;
        int stride = 1024 * 256;
        float acc = 0.f;
        for (int v = idx; v < N4; v += stride) {
            int flat = v << 2;                   // att is (B, T, L)
            int b  = flat >> 19;
            int t  = (flat >> 8) & (Tn - 1);
            int l0 = flat & (Ln - 1);
            int ili = ilen[b];
            int oli = olen[b];
            if (t >= oli) continue;
            float il = (float)ili, ol = (float)oli;
            float tf = (float)t / ol;
            float4 a = reinterpret_cast<const float4*>(att)[v];
            #pragma unroll
            for (int c = 0; c < 4; ++c) {
                int l = l0 + c;
                float av = (c == 0) ? a.x : (c == 1) ? a.y : (c == 2) ? a.z : a.w;
                if (l < ili) {
                    float d = (float)l / il - tf;
                    acc += (1.f - __expf(-d * d * 3.125f)) * av;
                }
            }
        }
        for (int off = 32; off > 0; off >>= 1) acc += __shfl_down(acc, off, 64);
        float* sw = smem;
        if ((tid & 63) == 0) sw[tid >> 6] = acc;
        __syncthreads();
        if (tid == 0) partial[j] = (sw[0] + sw[1]) + (sw[2] + sw[3]);
    }
}

// ---------------- backtrack: 256-thr staging, 4-deep window walk -> extents ----------------
// Words are stored bit-REVERSED (addc shift-accumulate); brev64 on load restores t-order.
__global__ void __launch_bounds__(256) k_backtrack(const uint64_t* __restrict__ bits,
                                                   const int* __restrict__ ilen,
                                                   const int* __restrict__ olen,
                                                   int2* __restrict__ ext) {
    __shared__ uint64_t sb[Ln * TB];   // 64 KB
    int b = blockIdx.x, tid = threadIdx.x;
    ext[b * Ln + tid] = make_int2(1, 0);          // init extents to empty
    const ulonglong2* g = (const ulonglong2*)(bits + (size_t)b * (Ln * TB));
    ulonglong2* s2 = (ulonglong2*)sb;
    #pragma unroll
    for (int i = 0; i < 16; ++i) s2[i * 256 + tid] = g[i * 256 + tid];
    __syncthreads();
    if (tid != 0) return;

    int tl = ilen[b], ml = olen[b];
    int2* eb = ext + b * Ln;
    int r = tl - 1, hi = ml - 1, p = ml - 2;
    if (p < 0) { eb[r] = make_int2(0, hi); return; }
    int c = p >> 6;
    #define LDW(RR) __builtin_bitreverse64(sb[(RR) * TB + c])
    uint64_t w0 = LDW(r);
    uint64_t w1 = LDW(r > 0 ? r - 1 : 0);
    uint64_t w2 = LDW(r > 1 ? r - 2 : 0);
    uint64_t w3 = LDW(r > 2 ? r - 3 : 0);
    int vd = 3;
    while (true) {
        int pb = p & 63;
        uint64_t mask = (pb == 63) ? ~0ull : ((1ull << (pb + 1)) - 1ull);
        uint64_t mm = w0 & mask;
        if (mm == 0) {
            p = (p & ~63) - 1;
            if (p < 0) { eb[r] = make_int2(0, hi); break; }
            c = p >> 6;
            w0 = LDW(r);
            w1 = LDW(r > 0 ? r - 1 : 0);
            w2 = LDW(r > 1 ? r - 2 : 0);
            w3 = LDW(r > 2 ? r - 3 : 0);
            vd = 3;
        } else {
            int q = 63 - __builtin_clzll(mm);
            int tq = (p & ~63) + q;
            eb[r] = make_int2(tq + 1, hi);
            r -= 1;
            if (r < 0) break;                   // saturation: remaining columns zero
            hi = tq;
            p = tq - 1;
            if (p < 0) { eb[r] = make_int2(0, hi); break; }
            w0 = w1; w1 = w2; w2 = w3; vd -= 1;
            int nc = p >> 6;
            if (nc != c || vd == 0) {
                c = nc;
                w0 = LDW(r);
                w1 = LDW(r > 0 ? r - 1 : 0);
                w2 = LDW(r > 1 ? r - 2 : 0);
                w3 = LDW(r > 2 ? r - 3 : 0);
                vd = 3;
            }
        }
    }
    #undef LDW
}

// ---------------- aligned-float4 fill from extents + fused final loss reduce ----------------
__global__ void k_fill(const int2* __restrict__ ext, const float* __restrict__ partial,
                       const int* __restrict__ olen, float* __restrict__ out) {
    const int NG = (Bn * Ln * Tn) / 4;          // 4,194,304 aligned float4 groups
    int idx = blockIdx.x * blockDim.x + threadIdx.x;
    int stride = gridDim.x * blockDim.x;
    for (int i = idx; i < NG; i += stride) {
        if (i == 0) {
            int2 e = ext[0];                     // out[1..3] = align f=0..2 (row 0)
            out[1] = (0 >= e.x && 0 <= e.y) ? 1.f : 0.f;
            out[2] = (1 >= e.x && 1 <= e.y) ? 1.f : 0.f;
            out[3] = (2 >= e.x && 2 <= e.y) ? 1.f : 0.f;
            int2 el = ext[Bn * Ln - 1];          // last element: row 8191, t=2047
            out[(size_t)Bn * Ln * Tn] = (2047 >= el.x && 2047 <= el.y) ? 1.f : 0.f;
            continue;
        }
        int f0 = 4 * i - 1;                      // align flat index of out[4i]
        int r0 = f0 >> 11;
        int t0 = f0 & 2047;
        int2 e0 = ext[r0];
        float4 v;
        if (t0 != 2047) {                        // all 4 in row r0
            v.x = (t0     >= e0.x && t0     <= e0.y) ? 1.f : 0.f;
            v.y = (t0 + 1 >= e0.x && t0 + 1 <= e0.y) ? 1.f : 0.f;
            v.z = (t0 + 2 >= e0.x && t0 + 2 <= e0.y) ? 1.f : 0.f;
            v.w = (t0 + 3 >= e0.x && t0 + 3 <= e0.y) ? 1.f : 0.f;
        } else {                                 // crosses into row r0+1 (t=0,1,2)
            int2 e1 = ext[r0 + 1];
            v.x = (2047 >= e0.x && 2047 <= e0.y) ? 1.f : 0.f;
            v.y = (0 >= e1.x && 0 <= e1.y) ? 1.f : 0.f;
            v.z = (1 >= e1.x && 1 <= e1.y) ? 1.f : 0.f;
            v.w = (2 >= e1.x && 2 <= e1.y) ? 1.f : 0.f;
        }
        *reinterpret_cast<float4*>(out + (size_t)4 * i) = v;
    }
    if (blockIdx.x == 0) {                       // fused deterministic loss reduce
        int tid = threadIdx.x;
        float acc = 0.f;
        for (int i = tid; i < 1024; i += 256) acc += partial[i];
        for (int off = 32; off > 0; off >>= 1) acc += __shfl_down(acc, off, 64);
        __shared__ float sw[4];
        if ((tid & 63) == 0) sw[tid >> 6] = acc;
        __syncthreads();
        if (tid == 0) {
            float tot = (sw[0] + sw[1]) + (sw[2] + sw[3]);
            int so = 0;
            for (int i = 0; i < Bn; ++i) so += olen[i];
            out[0] = tot / (float)so;
        }
    }
}

extern "C" void kernel_launch(void* const* d_in, const int* in_sizes, int n_in,
                              void* d_out, int out_size, void* d_ws, size_t ws_size,
                              hipStream_t stream) {
    const float* logp = (const float*)d_in[0];
    const float* att  = (const float*)d_in[1];
    const int* tlen   = (const int*)d_in[2];
    const int* mlen   = (const int*)d_in[3];
    float* out = (float*)d_out;
    uint64_t* bits = (uint64_t*)d_ws;                            // 2 MB
    float* partial = (float*)((char*)d_ws + 2097152);            // 4 KB
    int2* ext = (int2*)((char*)d_ws + 2101248);                  // 64 KB

    // 1) mega: forward DP (exclusive CUs via 96KB LDS, addc bit packing)
    //    + concurrent loss partials on the other 224 CUs
    k_mega<<<32 + 1024, 256, 0, stream>>>(logp, att, tlen, mlen, bits, partial);
    // 2) backtrack -> per-row run extents (brev64 on word loads)
    k_backtrack<<<Bn, 256, 0, stream>>>(bits, tlen, mlen, ext);
    // 3) write full 0/1 output from extents + final loss reduce
    k_fill<<<2048, 256, 0, stream>>>(ext, partial, mlen, out);
}